// Round 2
// baseline (6190.208 us; speedup 1.0000x reference)
//
#include <hip/hip_runtime.h>
#include <hip/hip_bf16.h>
#include <math.h>

#define N_NODES 100000
#define N_EDGES 1600000
#define N_FEAT 32
#define HIDDEN 128
#define N_GRAPHS 256
#define LN_EPS 1e-5f
#define BM 64
#define BK 32

// ---------------- degree (segment count over dst) ----------------
__global__ __launch_bounds__(256) void deg_kernel(const int* __restrict__ dst,
                                                  float* __restrict__ deg) {
    int e = blockIdx.x * blockDim.x + threadIdx.x;
    if (e < N_EDGES) atomicAdd(&deg[dst[e]], 1.0f);
}

// ---------------- input projection: h = x @ W_op + b_op ----------------
__global__ __launch_bounds__(256) void proj_kernel(const float* __restrict__ x,
                                                   const float* __restrict__ W,
                                                   const float* __restrict__ b,
                                                   float* __restrict__ h) {
    __shared__ float ws[N_FEAT][HIDDEN];   // 16KB
    __shared__ float bs[HIDDEN];
    __shared__ float xs[64][N_FEAT];       // 8KB
    int t = threadIdx.x;
    // load W_op: 4096 floats = 1024 float4
    #pragma unroll
    for (int i = 0; i < 4; ++i)
        ((float4*)&ws[0][0])[t + i * 256] = ((const float4*)W)[t + i * 256];
    if (t < 32) ((float4*)bs)[t] = ((const float4*)b)[t];
    int base = blockIdx.x * 64;
    // load x tile: 64x32 = 512 float4
    #pragma unroll
    for (int i = 0; i < 2; ++i) {
        int f4 = t + i * 256;
        int node = base + (f4 >> 3);
        float4 v = make_float4(0.f, 0.f, 0.f, 0.f);
        if (node < N_NODES) v = ((const float4*)x)[(size_t)node * 8 + (f4 & 7)];
        ((float4*)&xs[0][0])[f4] = v;
    }
    __syncthreads();
    int c0 = (t & 31) * 4;
    int nslot = t >> 5;  // 0..7
    for (int it = 0; it < 8; ++it) {
        int nl = nslot + it * 8;
        int node = base + nl;
        float acc0 = bs[c0], acc1 = bs[c0 + 1], acc2 = bs[c0 + 2], acc3 = bs[c0 + 3];
        #pragma unroll
        for (int k = 0; k < N_FEAT; ++k) {
            float a = xs[nl][k];
            float4 w = *(const float4*)&ws[k][c0];
            acc0 += a * w.x; acc1 += a * w.y; acc2 += a * w.z; acc3 += a * w.w;
        }
        if (node < N_NODES)
            *(float4*)&h[(size_t)node * HIDDEN + c0] = make_float4(acc0, acc1, acc2, acc3);
    }
}

// ---------------- edge scatter: agg[dst] += h[src] ----------------
__global__ __launch_bounds__(256) void scatter_kernel(const float* __restrict__ h,
                                                      const int* __restrict__ src,
                                                      const int* __restrict__ dst,
                                                      float* __restrict__ agg) {
    size_t tid = (size_t)blockIdx.x * blockDim.x + threadIdx.x;
    size_t e = tid >> 5;
    int f = (int)(tid & 31) * 4;
    if (e < N_EDGES) {
        int s = src[e], d = dst[e];
        float4 v = *(const float4*)(h + (size_t)s * HIDDEN + f);
        float* o = agg + (size_t)d * HIDDEN + f;
        atomicAdd(o + 0, v.x); atomicAdd(o + 1, v.y);
        atomicAdd(o + 2, v.z); atomicAdd(o + 3, v.w);
    }
}

// ---------------- fused layer: h = LN(ELU(aggscaled@W_l + b_l + h@W_r)) ----------------
__global__ __launch_bounds__(256) void layer_kernel(const float* __restrict__ agg,
                                                    const float* __restrict__ deg,
                                                    const float* __restrict__ W_l,
                                                    const float* __restrict__ b_l,
                                                    const float* __restrict__ W_r,
                                                    const float* __restrict__ gamma_,
                                                    const float* __restrict__ beta_,
                                                    float* __restrict__ h) {
    __shared__ float a_s[BK][BM + 4];     // 8.5KB, K-major so M is contiguous
    __shared__ float b_s[BK][HIDDEN];     // 16KB
    int t = threadIdx.x;
    int row0 = blockIdx.x * BM;
    int tn = t & 31;   // col group: cols tn*4..tn*4+3
    int tm = t >> 5;   // row group: rows tm*8..tm*8+7
    int c0 = tn * 4;
    float acc[8][4] = {};
    // K = 256: tiles 0..3 = agg (scaled by inv_deg) vs W_l, 4..7 = h vs W_r
    for (int kt = 0; kt < 8; ++kt) {
        const float* A = (kt < 4) ? agg : h;
        const float* W = (kt < 4) ? W_l : W_r;
        int kbase = (kt & 3) * BK;
        bool scaled = (kt < 4);
        // A tile: 64 rows x 32 k, each thread 2 float4 (transposed store)
        {
            int m = t >> 3;
            int kq = (t & 7) * 4;
            #pragma unroll
            for (int half = 0; half < 2; ++half) {
                int mm = m + half * 32;
                int node = row0 + mm;
                float4 v = make_float4(0.f, 0.f, 0.f, 0.f);
                if (node < N_NODES) {
                    v = *(const float4*)(A + (size_t)node * HIDDEN + kbase + kq);
                    if (scaled) {
                        float inv = 1.0f / fmaxf(deg[node], 1.0f);
                        v.x *= inv; v.y *= inv; v.z *= inv; v.w *= inv;
                    }
                }
                a_s[kq + 0][mm] = v.x; a_s[kq + 1][mm] = v.y;
                a_s[kq + 2][mm] = v.z; a_s[kq + 3][mm] = v.w;
            }
        }
        // B tile: 32 k x 128 cols, each thread 4 float4
        {
            int kk = t >> 5;
            int cc = (t & 31) * 4;
            #pragma unroll
            for (int i = 0; i < 4; ++i) {
                int k = kk + i * 8;
                *(float4*)&b_s[k][cc] = *(const float4*)(W + (size_t)(kbase + k) * HIDDEN + cc);
            }
        }
        __syncthreads();
        #pragma unroll 8
        for (int k = 0; k < BK; ++k) {
            float4 av0 = *(const float4*)&a_s[k][tm * 8];
            float4 av1 = *(const float4*)&a_s[k][tm * 8 + 4];
            float4 bv = *(const float4*)&b_s[k][c0];
            float av[8] = {av0.x, av0.y, av0.z, av0.w, av1.x, av1.y, av1.z, av1.w};
            #pragma unroll
            for (int r = 0; r < 8; ++r) {
                acc[r][0] += av[r] * bv.x; acc[r][1] += av[r] * bv.y;
                acc[r][2] += av[r] * bv.z; acc[r][3] += av[r] * bv.w;
            }
        }
        __syncthreads();
    }
    // epilogue: +b_l, ELU, LayerNorm (row = 32 lanes of same tm), in-place write
    float4 blv = *(const float4*)&b_l[c0];
    float4 gav = *(const float4*)&gamma_[c0];
    float4 bev = *(const float4*)&beta_[c0];
    float bl[4] = {blv.x, blv.y, blv.z, blv.w};
    float ga[4] = {gav.x, gav.y, gav.z, gav.w};
    float be[4] = {bev.x, bev.y, bev.z, bev.w};
    const float inv128 = 1.0f / 128.0f;
    #pragma unroll
    for (int r = 0; r < 8; ++r) {
        int node = row0 + tm * 8 + r;
        float v[4];
        float s = 0.f, sq = 0.f;
        #pragma unroll
        for (int j = 0; j < 4; ++j) {
            float xv = acc[r][j] + bl[j];
            xv = (xv > 0.f) ? xv : expm1f(xv);
            v[j] = xv; s += xv; sq += xv * xv;
        }
        #pragma unroll
        for (int m = 16; m >= 1; m >>= 1) {
            s += __shfl_xor(s, m, 64);
            sq += __shfl_xor(sq, m, 64);
        }
        float mu = s * inv128;
        float var = sq * inv128 - mu * mu;
        float rstd = rsqrtf(var + LN_EPS);
        if (node < N_NODES) {
            float4 o;
            o.x = (v[0] - mu) * rstd * ga[0] + be[0];
            o.y = (v[1] - mu) * rstd * ga[1] + be[1];
            o.z = (v[2] - mu) * rstd * ga[2] + be[2];
            o.w = (v[3] - mu) * rstd * ga[3] + be[3];
            *(float4*)&h[(size_t)node * HIDDEN + c0] = o;
        }
    }
}

// ---------------- pooling: pooled[g] += h[node], cnt[g] += 1 ----------------
__global__ __launch_bounds__(256) void pool_kernel(const float* __restrict__ h,
                                                   const int* __restrict__ batch,
                                                   float* __restrict__ pooled,
                                                   float* __restrict__ cnt) {
    size_t tid = (size_t)blockIdx.x * blockDim.x + threadIdx.x;
    int node = (int)(tid >> 5);
    int c = (int)(tid & 31) * 4;
    if (node < N_NODES) {
        int g = batch[node];
        float4 v = *(const float4*)(h + (size_t)node * HIDDEN + c);
        float* o = pooled + (size_t)g * HIDDEN + c;
        atomicAdd(o + 0, v.x); atomicAdd(o + 1, v.y);
        atomicAdd(o + 2, v.z); atomicAdd(o + 3, v.w);
        if (c == 0) atomicAdd(&cnt[g], 1.0f);
    }
}

// ---------------- heads ----------------
__global__ __launch_bounds__(64) void head_kernel(const float* __restrict__ pooled,
                                                  const float* __restrict__ cnt,
                                                  const float* __restrict__ W_mem,
                                                  const float* __restrict__ b_mem,
                                                  const float* __restrict__ W_time,
                                                  const float* __restrict__ b_time,
                                                  float* __restrict__ out) {
    int g = blockIdx.x;
    int l = threadIdx.x;  // 0..63
    float ic = 1.0f / fmaxf(cnt[g], 1.0f);
    float p0 = pooled[(size_t)g * HIDDEN + l] * ic;
    float p1 = pooled[(size_t)g * HIDDEN + l + 64] * ic;
    float dm = p0 * W_mem[l] + p1 * W_mem[l + 64];
    float dt = p0 * W_time[l] + p1 * W_time[l + 64];
    #pragma unroll
    for (int m = 32; m >= 1; m >>= 1) {
        dm += __shfl_xor(dm, m, 64);
        dt += __shfl_xor(dt, m, 64);
    }
    if (l == 0) {
        out[g] = dm + b_mem[0];
        out[N_GRAPHS + g] = dt + b_time[0];
    }
}

extern "C" void kernel_launch(void* const* d_in, const int* in_sizes, int n_in,
                              void* d_out, int out_size, void* d_ws, size_t ws_size,
                              hipStream_t stream) {
    const float* x      = (const float*)d_in[0];
    const int*   edge   = (const int*)d_in[1];
    const int*   batch  = (const int*)d_in[2];
    const float* W_op   = (const float*)d_in[3];
    const float* b_op   = (const float*)d_in[4];
    const float* W_l    = (const float*)d_in[5];
    const float* b_l    = (const float*)d_in[6];
    const float* W_r    = (const float*)d_in[7];
    const float* gamma_ = (const float*)d_in[8];
    const float* beta_  = (const float*)d_in[9];
    const float* W_mem  = (const float*)d_in[10];
    const float* b_mem  = (const float*)d_in[11];
    const float* W_time = (const float*)d_in[12];
    const float* b_time = (const float*)d_in[13];
    const int* src = edge;
    const int* dst = edge + N_EDGES;

    char* ws = (char*)d_ws;
    const size_t hbytes = (size_t)N_NODES * HIDDEN * sizeof(float);  // 51.2MB
    float* h      = (float*)ws;
    float* agg    = (float*)(ws + hbytes);
    float* deg    = (float*)(ws + 2 * hbytes);
    float* pooled = deg + N_NODES;
    float* cnt    = pooled + N_GRAPHS * HIDDEN;

    // zero deg + pooled + cnt (ws is poisoned 0xAA before every call)
    hipMemsetAsync(deg, 0, (N_NODES + N_GRAPHS * HIDDEN + N_GRAPHS) * sizeof(float), stream);
    deg_kernel<<<(N_EDGES + 255) / 256, 256, 0, stream>>>(dst, deg);
    proj_kernel<<<(N_NODES + 63) / 64, 256, 0, stream>>>(x, W_op, b_op, h);

    for (int layer = 0; layer < 2; ++layer) {
        hipMemsetAsync(agg, 0, hbytes, stream);
        scatter_kernel<<<(int)(((size_t)N_EDGES * 32 + 255) / 256), 256, 0, stream>>>(h, src, dst, agg);
        layer_kernel<<<(N_NODES + BM - 1) / BM, 256, 0, stream>>>(agg, deg, W_l, b_l, W_r, gamma_, beta_, h);
    }

    pool_kernel<<<(int)(((size_t)N_NODES * 32 + 255) / 256), 256, 0, stream>>>(h, batch, pooled, cnt);
    head_kernel<<<N_GRAPHS, 64, 0, stream>>>(pooled, cnt, W_mem, b_mem, W_time, b_time, (float*)d_out);
}

// Round 3
// 1186.156 us; speedup vs baseline: 5.2187x; 5.2187x over previous
//
#include <hip/hip_runtime.h>
#include <hip/hip_bf16.h>
#include <math.h>

#define N_NODES 100000
#define N_EDGES 1600000
#define N_FEAT 32
#define HIDDEN 128
#define N_GRAPHS 256
#define LN_EPS 1e-5f
#define BM 64
#define BK 32
#define NBLK_SCAN ((N_NODES + 255) / 256)   // 391

// ---------------- int degree over dst ----------------
__global__ __launch_bounds__(256) void deg_int_kernel(const int* __restrict__ dst,
                                                      int* __restrict__ degi) {
    int e = blockIdx.x * blockDim.x + threadIdx.x;
    if (e < N_EDGES) atomicAdd(&degi[dst[e]], 1);
}

// ---------------- scan step 1: per-block sums ----------------
__global__ __launch_bounds__(256) void scan_block_sums(const int* __restrict__ degi,
                                                       int* __restrict__ bsum) {
    __shared__ int red[256];
    int t = threadIdx.x;
    int i = blockIdx.x * 256 + t;
    red[t] = (i < N_NODES) ? degi[i] : 0;
    __syncthreads();
    #pragma unroll
    for (int off = 128; off > 0; off >>= 1) {
        if (t < off) red[t] += red[t + off];
        __syncthreads();
    }
    if (t == 0) bsum[blockIdx.x] = red[0];
}

// ---------------- scan step 2: exclusive scan of block sums (1 block) ----------------
__global__ __launch_bounds__(512) void scan_partials(const int* __restrict__ bsum,
                                                     int* __restrict__ boff) {
    __shared__ int s[512];
    int t = threadIdx.x;
    int v = (t < NBLK_SCAN) ? bsum[t] : 0;
    s[t] = v;
    __syncthreads();
    for (int off = 1; off < 512; off <<= 1) {
        int x = s[t];
        if (t >= off) x += s[t - off];
        __syncthreads();
        s[t] = x;
        __syncthreads();
    }
    if (t < NBLK_SCAN) boff[t] = s[t] - v;   // exclusive
}

// ---------------- scan step 3: per-element exclusive offsets + cursor copy ----------------
__global__ __launch_bounds__(256) void scan_final(const int* __restrict__ degi,
                                                  const int* __restrict__ boff,
                                                  int* __restrict__ offsets,
                                                  int* __restrict__ cursor) {
    __shared__ int s[256];
    int t = threadIdx.x;
    int i = blockIdx.x * 256 + t;
    int v = (i < N_NODES) ? degi[i] : 0;
    s[t] = v;
    __syncthreads();
    for (int off = 1; off < 256; off <<= 1) {
        int x = s[t];
        if (t >= off) x += s[t - off];
        __syncthreads();
        s[t] = x;
        __syncthreads();
    }
    if (i < N_NODES) {
        int ex = s[t] - v + boff[blockIdx.x];
        offsets[i] = ex;
        cursor[i] = ex;
    }
}

// ---------------- CSR fill: csr[slot] = src, bucketed by dst ----------------
__global__ __launch_bounds__(256) void fill_csr(const int* __restrict__ src,
                                                const int* __restrict__ dst,
                                                int* __restrict__ cursor,
                                                int* __restrict__ csr) {
    int e = blockIdx.x * blockDim.x + threadIdx.x;
    if (e < N_EDGES) {
        int pos = atomicAdd(&cursor[dst[e]], 1);
        csr[pos] = src[e];
    }
}

// ---------------- gather: agg[n] = mean over neighbors of h[src] ----------------
__global__ __launch_bounds__(256) void gather_kernel(const float* __restrict__ h,
                                                     const int* __restrict__ csr,
                                                     const int* __restrict__ offsets,
                                                     const int* __restrict__ degi,
                                                     float* __restrict__ agg) {
    int node = (int)(((size_t)blockIdx.x * blockDim.x + threadIdx.x) >> 5);
    int lane = threadIdx.x & 31;
    if (node >= N_NODES) return;
    int st = offsets[node];
    int dn = degi[node];
    float4 a0 = make_float4(0.f, 0.f, 0.f, 0.f);
    float4 a1 = make_float4(0.f, 0.f, 0.f, 0.f);
    int i = 0;
    for (; i + 2 <= dn; i += 2) {
        int s0 = csr[st + i];
        int s1 = csr[st + i + 1];
        float4 v0 = *(const float4*)(h + (size_t)s0 * HIDDEN + lane * 4);
        float4 v1 = *(const float4*)(h + (size_t)s1 * HIDDEN + lane * 4);
        a0.x += v0.x; a0.y += v0.y; a0.z += v0.z; a0.w += v0.w;
        a1.x += v1.x; a1.y += v1.y; a1.z += v1.z; a1.w += v1.w;
    }
    if (i < dn) {
        int s0 = csr[st + i];
        float4 v0 = *(const float4*)(h + (size_t)s0 * HIDDEN + lane * 4);
        a0.x += v0.x; a0.y += v0.y; a0.z += v0.z; a0.w += v0.w;
    }
    float inv = 1.0f / fmaxf((float)dn, 1.0f);
    float4 r;
    r.x = (a0.x + a1.x) * inv;
    r.y = (a0.y + a1.y) * inv;
    r.z = (a0.z + a1.z) * inv;
    r.w = (a0.w + a1.w) * inv;
    *(float4*)(agg + (size_t)node * HIDDEN + lane * 4) = r;
}

// ---------------- input projection: h = x @ W_op + b_op ----------------
__global__ __launch_bounds__(256) void proj_kernel(const float* __restrict__ x,
                                                   const float* __restrict__ W,
                                                   const float* __restrict__ b,
                                                   float* __restrict__ h) {
    __shared__ float ws[N_FEAT][HIDDEN];   // 16KB
    __shared__ float bs[HIDDEN];
    __shared__ float xs[64][N_FEAT];       // 8KB
    int t = threadIdx.x;
    #pragma unroll
    for (int i = 0; i < 4; ++i)
        ((float4*)&ws[0][0])[t + i * 256] = ((const float4*)W)[t + i * 256];
    if (t < 32) ((float4*)bs)[t] = ((const float4*)b)[t];
    int base = blockIdx.x * 64;
    #pragma unroll
    for (int i = 0; i < 2; ++i) {
        int f4 = t + i * 256;
        int node = base + (f4 >> 3);
        float4 v = make_float4(0.f, 0.f, 0.f, 0.f);
        if (node < N_NODES) v = ((const float4*)x)[(size_t)node * 8 + (f4 & 7)];
        ((float4*)&xs[0][0])[f4] = v;
    }
    __syncthreads();
    int c0 = (t & 31) * 4;
    int nslot = t >> 5;  // 0..7
    for (int it = 0; it < 8; ++it) {
        int nl = nslot + it * 8;
        int node = base + nl;
        float acc0 = bs[c0], acc1 = bs[c0 + 1], acc2 = bs[c0 + 2], acc3 = bs[c0 + 3];
        #pragma unroll
        for (int k = 0; k < N_FEAT; ++k) {
            float a = xs[nl][k];
            float4 w = *(const float4*)&ws[k][c0];
            acc0 += a * w.x; acc1 += a * w.y; acc2 += a * w.z; acc3 += a * w.w;
        }
        if (node < N_NODES)
            *(float4*)&h[(size_t)node * HIDDEN + c0] = make_float4(acc0, acc1, acc2, acc3);
    }
}

// ---------------- fused layer: h = LN(ELU(agg@W_l + b_l + h@W_r)) ----------------
__global__ __launch_bounds__(256) void layer_kernel(const float* __restrict__ agg,
                                                    const float* __restrict__ W_l,
                                                    const float* __restrict__ b_l,
                                                    const float* __restrict__ W_r,
                                                    const float* __restrict__ gamma_,
                                                    const float* __restrict__ beta_,
                                                    float* __restrict__ h) {
    __shared__ float a_s[BK][BM + 4];     // 8.5KB, K-major so M is contiguous
    __shared__ float b_s[BK][HIDDEN];     // 16KB
    int t = threadIdx.x;
    int row0 = blockIdx.x * BM;
    int tn = t & 31;   // col group: cols tn*4..tn*4+3
    int tm = t >> 5;   // row group: rows tm*8..tm*8+7
    int c0 = tn * 4;
    float acc[8][4] = {};
    // K = 256: tiles 0..3 = agg vs W_l, 4..7 = h vs W_r
    for (int kt = 0; kt < 8; ++kt) {
        const float* A = (kt < 4) ? agg : h;
        const float* W = (kt < 4) ? W_l : W_r;
        int kbase = (kt & 3) * BK;
        // A tile: 64 rows x 32 k, each thread 2 float4 (transposed store)
        {
            int m = t >> 3;
            int kq = (t & 7) * 4;
            #pragma unroll
            for (int half = 0; half < 2; ++half) {
                int mm = m + half * 32;
                int node = row0 + mm;
                float4 v = make_float4(0.f, 0.f, 0.f, 0.f);
                if (node < N_NODES)
                    v = *(const float4*)(A + (size_t)node * HIDDEN + kbase + kq);
                a_s[kq + 0][mm] = v.x; a_s[kq + 1][mm] = v.y;
                a_s[kq + 2][mm] = v.z; a_s[kq + 3][mm] = v.w;
            }
        }
        // B tile: 32 k x 128 cols, each thread 4 float4
        {
            int kk = t >> 5;
            int cc = (t & 31) * 4;
            #pragma unroll
            for (int i = 0; i < 4; ++i) {
                int k = kk + i * 8;
                *(float4*)&b_s[k][cc] = *(const float4*)(W + (size_t)(kbase + k) * HIDDEN + cc);
            }
        }
        __syncthreads();
        #pragma unroll 8
        for (int k = 0; k < BK; ++k) {
            float4 av0 = *(const float4*)&a_s[k][tm * 8];
            float4 av1 = *(const float4*)&a_s[k][tm * 8 + 4];
            float4 bv = *(const float4*)&b_s[k][c0];
            float av[8] = {av0.x, av0.y, av0.z, av0.w, av1.x, av1.y, av1.z, av1.w};
            #pragma unroll
            for (int r = 0; r < 8; ++r) {
                acc[r][0] += av[r] * bv.x; acc[r][1] += av[r] * bv.y;
                acc[r][2] += av[r] * bv.z; acc[r][3] += av[r] * bv.w;
            }
        }
        __syncthreads();
    }
    // epilogue: +b_l, ELU, LayerNorm (row = 32 lanes of same tm), in-place write
    float4 blv = *(const float4*)&b_l[c0];
    float4 gav = *(const float4*)&gamma_[c0];
    float4 bev = *(const float4*)&beta_[c0];
    float bl[4] = {blv.x, blv.y, blv.z, blv.w};
    float ga[4] = {gav.x, gav.y, gav.z, gav.w};
    float be[4] = {bev.x, bev.y, bev.z, bev.w};
    const float inv128 = 1.0f / 128.0f;
    #pragma unroll
    for (int r = 0; r < 8; ++r) {
        int node = row0 + tm * 8 + r;
        float v[4];
        float s = 0.f, sq = 0.f;
        #pragma unroll
        for (int j = 0; j < 4; ++j) {
            float xv = acc[r][j] + bl[j];
            xv = (xv > 0.f) ? xv : expm1f(xv);
            v[j] = xv; s += xv; sq += xv * xv;
        }
        #pragma unroll
        for (int m = 16; m >= 1; m >>= 1) {
            s += __shfl_xor(s, m, 64);
            sq += __shfl_xor(sq, m, 64);
        }
        float mu = s * inv128;
        float var = sq * inv128 - mu * mu;
        float rstd = rsqrtf(var + LN_EPS);
        if (node < N_NODES) {
            float4 o;
            o.x = (v[0] - mu) * rstd * ga[0] + be[0];
            o.y = (v[1] - mu) * rstd * ga[1] + be[1];
            o.z = (v[2] - mu) * rstd * ga[2] + be[2];
            o.w = (v[3] - mu) * rstd * ga[3] + be[3];
            *(float4*)&h[(size_t)node * HIDDEN + c0] = o;
        }
    }
}

// ---------------- pooling: pooled[g] += h[node], cnt[g] += 1 ----------------
__global__ __launch_bounds__(256) void pool_kernel(const float* __restrict__ h,
                                                   const int* __restrict__ batch,
                                                   float* __restrict__ pooled,
                                                   float* __restrict__ cnt) {
    size_t tid = (size_t)blockIdx.x * blockDim.x + threadIdx.x;
    int node = (int)(tid >> 5);
    int c = (int)(tid & 31) * 4;
    if (node < N_NODES) {
        int g = batch[node];
        float4 v = *(const float4*)(h + (size_t)node * HIDDEN + c);
        float* o = pooled + (size_t)g * HIDDEN + c;
        atomicAdd(o + 0, v.x); atomicAdd(o + 1, v.y);
        atomicAdd(o + 2, v.z); atomicAdd(o + 3, v.w);
        if (c == 0) atomicAdd(&cnt[g], 1.0f);
    }
}

// ---------------- heads ----------------
__global__ __launch_bounds__(64) void head_kernel(const float* __restrict__ pooled,
                                                  const float* __restrict__ cnt,
                                                  const float* __restrict__ W_mem,
                                                  const float* __restrict__ b_mem,
                                                  const float* __restrict__ W_time,
                                                  const float* __restrict__ b_time,
                                                  float* __restrict__ out) {
    int g = blockIdx.x;
    int l = threadIdx.x;  // 0..63
    float ic = 1.0f / fmaxf(cnt[g], 1.0f);
    float p0 = pooled[(size_t)g * HIDDEN + l] * ic;
    float p1 = pooled[(size_t)g * HIDDEN + l + 64] * ic;
    float dm = p0 * W_mem[l] + p1 * W_mem[l + 64];
    float dt = p0 * W_time[l] + p1 * W_time[l + 64];
    #pragma unroll
    for (int m = 32; m >= 1; m >>= 1) {
        dm += __shfl_xor(dm, m, 64);
        dt += __shfl_xor(dt, m, 64);
    }
    if (l == 0) {
        out[g] = dm + b_mem[0];
        out[N_GRAPHS + g] = dt + b_time[0];
    }
}

extern "C" void kernel_launch(void* const* d_in, const int* in_sizes, int n_in,
                              void* d_out, int out_size, void* d_ws, size_t ws_size,
                              hipStream_t stream) {
    const float* x      = (const float*)d_in[0];
    const int*   edge   = (const int*)d_in[1];
    const int*   batch  = (const int*)d_in[2];
    const float* W_op   = (const float*)d_in[3];
    const float* b_op   = (const float*)d_in[4];
    const float* W_l    = (const float*)d_in[5];
    const float* b_l    = (const float*)d_in[6];
    const float* W_r    = (const float*)d_in[7];
    const float* gamma_ = (const float*)d_in[8];
    const float* beta_  = (const float*)d_in[9];
    const float* W_mem  = (const float*)d_in[10];
    const float* b_mem  = (const float*)d_in[11];
    const float* W_time = (const float*)d_in[12];
    const float* b_time = (const float*)d_in[13];
    const int* src = edge;
    const int* dst = edge + N_EDGES;

    char* ws = (char*)d_ws;
    const size_t hbytes = (size_t)N_NODES * HIDDEN * sizeof(float);  // 51.2MB
    float* h       = (float*)ws;
    float* agg     = (float*)(ws + hbytes);
    char*  p       = ws + 2 * hbytes;
    int*   degi    = (int*)p;                 p += (size_t)N_NODES * 4;
    int*   offsets = (int*)p;                 p += (size_t)N_NODES * 4;
    int*   cursor  = (int*)p;                 p += (size_t)N_NODES * 4;
    int*   csr     = (int*)p;                 p += (size_t)N_EDGES * 4;
    int*   bsum    = (int*)p;                 p += 2048;
    int*   boff    = (int*)p;                 p += 2048;
    float* pooled  = (float*)p;               p += (size_t)N_GRAPHS * HIDDEN * 4;
    float* cnt     = (float*)p;               p += (size_t)N_GRAPHS * 4;

    // zero degree counters + pooled/cnt (ws is re-poisoned 0xAA before every call)
    hipMemsetAsync(degi, 0, (size_t)N_NODES * 4, stream);
    hipMemsetAsync(pooled, 0, (size_t)(N_GRAPHS * HIDDEN + N_GRAPHS) * 4, stream);

    // CSR build
    deg_int_kernel<<<(N_EDGES + 255) / 256, 256, 0, stream>>>(dst, degi);
    scan_block_sums<<<NBLK_SCAN, 256, 0, stream>>>(degi, bsum);
    scan_partials<<<1, 512, 0, stream>>>(bsum, boff);
    scan_final<<<NBLK_SCAN, 256, 0, stream>>>(degi, boff, offsets, cursor);
    fill_csr<<<(N_EDGES + 255) / 256, 256, 0, stream>>>(src, dst, cursor, csr);

    // input projection
    proj_kernel<<<(N_NODES + 63) / 64, 256, 0, stream>>>(x, W_op, b_op, h);

    // layers
    for (int layer = 0; layer < 2; ++layer) {
        gather_kernel<<<(int)(((size_t)N_NODES * 32 + 255) / 256), 256, 0, stream>>>(
            h, csr, offsets, degi, agg);
        layer_kernel<<<(N_NODES + BM - 1) / BM, 256, 0, stream>>>(
            agg, W_l, b_l, W_r, gamma_, beta_, h);
    }

    // pooling + heads
    pool_kernel<<<(int)(((size_t)N_NODES * 32 + 255) / 256), 256, 0, stream>>>(h, batch, pooled, cnt);
    head_kernel<<<N_GRAPHS, 64, 0, stream>>>(pooled, cnt, W_mem, b_mem, W_time, b_time, (float*)d_out);
}

// Round 4
// 773.690 us; speedup vs baseline: 8.0009x; 1.5331x over previous
//
#include <hip/hip_runtime.h>
#include <hip/hip_bf16.h>
#include <math.h>

#define N_NODES 100000
#define N_EDGES 1600000
#define N_FEAT 32
#define HIDDEN 128
#define N_GRAPHS 256
#define LN_EPS 1e-5f
#define BM 64
#define BK 32
#define NBLK_SCAN ((N_NODES + 255) / 256)   // 391

// ---------------- int degree over dst ----------------
__global__ __launch_bounds__(256) void deg_int_kernel(const int* __restrict__ dst,
                                                      int* __restrict__ degi) {
    int e = blockIdx.x * blockDim.x + threadIdx.x;
    if (e < N_EDGES) atomicAdd(&degi[dst[e]], 1);
}

// ---------------- scan step 1: per-block sums ----------------
__global__ __launch_bounds__(256) void scan_block_sums(const int* __restrict__ degi,
                                                       int* __restrict__ bsum) {
    __shared__ int red[256];
    int t = threadIdx.x;
    int i = blockIdx.x * 256 + t;
    red[t] = (i < N_NODES) ? degi[i] : 0;
    __syncthreads();
    #pragma unroll
    for (int off = 128; off > 0; off >>= 1) {
        if (t < off) red[t] += red[t + off];
        __syncthreads();
    }
    if (t == 0) bsum[blockIdx.x] = red[0];
}

// ---------------- scan step 2: exclusive scan of block sums (1 block) ----------------
__global__ __launch_bounds__(512) void scan_partials(const int* __restrict__ bsum,
                                                     int* __restrict__ boff) {
    __shared__ int s[512];
    int t = threadIdx.x;
    int v = (t < NBLK_SCAN) ? bsum[t] : 0;
    s[t] = v;
    __syncthreads();
    for (int off = 1; off < 512; off <<= 1) {
        int x = s[t];
        if (t >= off) x += s[t - off];
        __syncthreads();
        s[t] = x;
        __syncthreads();
    }
    if (t < NBLK_SCAN) boff[t] = s[t] - v;   // exclusive
}

// ---------------- scan step 3: per-element exclusive offsets + cursor copy ----------------
__global__ __launch_bounds__(256) void scan_final(const int* __restrict__ degi,
                                                  const int* __restrict__ boff,
                                                  int* __restrict__ offsets,
                                                  int* __restrict__ cursor) {
    __shared__ int s[256];
    int t = threadIdx.x;
    int i = blockIdx.x * 256 + t;
    int v = (i < N_NODES) ? degi[i] : 0;
    s[t] = v;
    __syncthreads();
    for (int off = 1; off < 256; off <<= 1) {
        int x = s[t];
        if (t >= off) x += s[t - off];
        __syncthreads();
        s[t] = x;
        __syncthreads();
    }
    if (i < N_NODES) {
        int ex = s[t] - v + boff[blockIdx.x];
        offsets[i] = ex;
        cursor[i] = ex;
    }
}

// ---------------- CSR fill: csr[slot] = src, bucketed by dst ----------------
__global__ __launch_bounds__(256) void fill_csr(const int* __restrict__ src,
                                                const int* __restrict__ dst,
                                                int* __restrict__ cursor,
                                                int* __restrict__ csr) {
    int e = blockIdx.x * blockDim.x + threadIdx.x;
    if (e < N_EDGES) {
        int pos = atomicAdd(&cursor[dst[e]], 1);
        csr[pos] = src[e];
    }
}

// ---------------- gather: agg[n] = mean over neighbors of h[src] ----------------
__global__ __launch_bounds__(256) void gather_kernel(const float* __restrict__ h,
                                                     const int* __restrict__ csr,
                                                     const int* __restrict__ offsets,
                                                     const int* __restrict__ degi,
                                                     float* __restrict__ agg) {
    int node = (int)(((size_t)blockIdx.x * blockDim.x + threadIdx.x) >> 5);
    int lane = threadIdx.x & 31;
    if (node >= N_NODES) return;
    int st = offsets[node];
    int dn = degi[node];
    float4 a0 = make_float4(0.f, 0.f, 0.f, 0.f);
    float4 a1 = make_float4(0.f, 0.f, 0.f, 0.f);
    int i = 0;
    for (; i + 2 <= dn; i += 2) {
        int s0 = csr[st + i];
        int s1 = csr[st + i + 1];
        float4 v0 = *(const float4*)(h + (size_t)s0 * HIDDEN + lane * 4);
        float4 v1 = *(const float4*)(h + (size_t)s1 * HIDDEN + lane * 4);
        a0.x += v0.x; a0.y += v0.y; a0.z += v0.z; a0.w += v0.w;
        a1.x += v1.x; a1.y += v1.y; a1.z += v1.z; a1.w += v1.w;
    }
    if (i < dn) {
        int s0 = csr[st + i];
        float4 v0 = *(const float4*)(h + (size_t)s0 * HIDDEN + lane * 4);
        a0.x += v0.x; a0.y += v0.y; a0.z += v0.z; a0.w += v0.w;
    }
    float inv = 1.0f / fmaxf((float)dn, 1.0f);
    float4 r;
    r.x = (a0.x + a1.x) * inv;
    r.y = (a0.y + a1.y) * inv;
    r.z = (a0.z + a1.z) * inv;
    r.w = (a0.w + a1.w) * inv;
    *(float4*)(agg + (size_t)node * HIDDEN + lane * 4) = r;
}

// ---------------- input projection: h = x @ W_op + b_op ----------------
__global__ __launch_bounds__(256) void proj_kernel(const float* __restrict__ x,
                                                   const float* __restrict__ W,
                                                   const float* __restrict__ b,
                                                   float* __restrict__ h) {
    __shared__ float ws[N_FEAT][HIDDEN];   // 16KB
    __shared__ float bs[HIDDEN];
    __shared__ float xs[64][N_FEAT];       // 8KB
    int t = threadIdx.x;
    #pragma unroll
    for (int i = 0; i < 4; ++i)
        ((float4*)&ws[0][0])[t + i * 256] = ((const float4*)W)[t + i * 256];
    if (t < 32) ((float4*)bs)[t] = ((const float4*)b)[t];
    int base = blockIdx.x * 64;
    #pragma unroll
    for (int i = 0; i < 2; ++i) {
        int f4 = t + i * 256;
        int node = base + (f4 >> 3);
        float4 v = make_float4(0.f, 0.f, 0.f, 0.f);
        if (node < N_NODES) v = ((const float4*)x)[(size_t)node * 8 + (f4 & 7)];
        ((float4*)&xs[0][0])[f4] = v;
    }
    __syncthreads();
    int c0 = (t & 31) * 4;
    int nslot = t >> 5;  // 0..7
    for (int it = 0; it < 8; ++it) {
        int nl = nslot + it * 8;
        int node = base + nl;
        float acc0 = bs[c0], acc1 = bs[c0 + 1], acc2 = bs[c0 + 2], acc3 = bs[c0 + 3];
        #pragma unroll
        for (int k = 0; k < N_FEAT; ++k) {
            float a = xs[nl][k];
            float4 w = *(const float4*)&ws[k][c0];
            acc0 += a * w.x; acc1 += a * w.y; acc2 += a * w.z; acc3 += a * w.w;
        }
        if (node < N_NODES)
            *(float4*)&h[(size_t)node * HIDDEN + c0] = make_float4(acc0, acc1, acc2, acc3);
    }
}

// ---------------- fused layer: h = LN(ELU(agg@W_l + b_l + h@W_r)) ----------------
__global__ __launch_bounds__(256) void layer_kernel(const float* __restrict__ agg,
                                                    const float* __restrict__ W_l,
                                                    const float* __restrict__ b_l,
                                                    const float* __restrict__ W_r,
                                                    const float* __restrict__ gamma_,
                                                    const float* __restrict__ beta_,
                                                    float* __restrict__ h) {
    __shared__ float a_s[BK][BM + 4];     // 8.5KB, K-major so M is contiguous
    __shared__ float b_s[BK][HIDDEN];     // 16KB
    int t = threadIdx.x;
    int row0 = blockIdx.x * BM;
    int tn = t & 31;   // col group: cols tn*4..tn*4+3
    int tm = t >> 5;   // row group: rows tm*8..tm*8+7
    int c0 = tn * 4;
    float acc[8][4] = {};
    // K = 256: tiles 0..3 = agg vs W_l, 4..7 = h vs W_r
    for (int kt = 0; kt < 8; ++kt) {
        const float* A = (kt < 4) ? agg : h;
        const float* W = (kt < 4) ? W_l : W_r;
        int kbase = (kt & 3) * BK;
        // A tile: 64 rows x 32 k, each thread 2 float4 (transposed store)
        {
            int m = t >> 3;
            int kq = (t & 7) * 4;
            #pragma unroll
            for (int half = 0; half < 2; ++half) {
                int mm = m + half * 32;
                int node = row0 + mm;
                float4 v = make_float4(0.f, 0.f, 0.f, 0.f);
                if (node < N_NODES)
                    v = *(const float4*)(A + (size_t)node * HIDDEN + kbase + kq);
                a_s[kq + 0][mm] = v.x; a_s[kq + 1][mm] = v.y;
                a_s[kq + 2][mm] = v.z; a_s[kq + 3][mm] = v.w;
            }
        }
        // B tile: 32 k x 128 cols, each thread 4 float4
        {
            int kk = t >> 5;
            int cc = (t & 31) * 4;
            #pragma unroll
            for (int i = 0; i < 4; ++i) {
                int k = kk + i * 8;
                *(float4*)&b_s[k][cc] = *(const float4*)(W + (size_t)(kbase + k) * HIDDEN + cc);
            }
        }
        __syncthreads();
        #pragma unroll 8
        for (int k = 0; k < BK; ++k) {
            float4 av0 = *(const float4*)&a_s[k][tm * 8];
            float4 av1 = *(const float4*)&a_s[k][tm * 8 + 4];
            float4 bv = *(const float4*)&b_s[k][c0];
            float av[8] = {av0.x, av0.y, av0.z, av0.w, av1.x, av1.y, av1.z, av1.w};
            #pragma unroll
            for (int r = 0; r < 8; ++r) {
                acc[r][0] += av[r] * bv.x; acc[r][1] += av[r] * bv.y;
                acc[r][2] += av[r] * bv.z; acc[r][3] += av[r] * bv.w;
            }
        }
        __syncthreads();
    }
    // epilogue: +b_l, ELU, LayerNorm (row = 32 lanes of same tm), in-place write
    float4 blv = *(const float4*)&b_l[c0];
    float4 gav = *(const float4*)&gamma_[c0];
    float4 bev = *(const float4*)&beta_[c0];
    float bl[4] = {blv.x, blv.y, blv.z, blv.w};
    float ga[4] = {gav.x, gav.y, gav.z, gav.w};
    float be[4] = {bev.x, bev.y, bev.z, bev.w};
    const float inv128 = 1.0f / 128.0f;
    #pragma unroll
    for (int r = 0; r < 8; ++r) {
        int node = row0 + tm * 8 + r;
        float v[4];
        float s = 0.f, sq = 0.f;
        #pragma unroll
        for (int j = 0; j < 4; ++j) {
            float xv = acc[r][j] + bl[j];
            xv = (xv > 0.f) ? xv : expm1f(xv);
            v[j] = xv; s += xv; sq += xv * xv;
        }
        #pragma unroll
        for (int m = 16; m >= 1; m >>= 1) {
            s += __shfl_xor(s, m, 64);
            sq += __shfl_xor(sq, m, 64);
        }
        float mu = s * inv128;
        float var = sq * inv128 - mu * mu;
        float rstd = rsqrtf(var + LN_EPS);
        if (node < N_NODES) {
            float4 o;
            o.x = (v[0] - mu) * rstd * ga[0] + be[0];
            o.y = (v[1] - mu) * rstd * ga[1] + be[1];
            o.z = (v[2] - mu) * rstd * ga[2] + be[2];
            o.w = (v[3] - mu) * rstd * ga[3] + be[3];
            *(float4*)&h[(size_t)node * HIDDEN + c0] = o;
        }
    }
}

// ---------------- fused pool + heads: one block per graph (batch is sorted) ----------------
__global__ __launch_bounds__(256) void pool_head_kernel(const float* __restrict__ h,
                                                        const int* __restrict__ batch,
                                                        const float* __restrict__ W_mem,
                                                        const float* __restrict__ b_mem,
                                                        const float* __restrict__ W_time,
                                                        const float* __restrict__ b_time,
                                                        float* __restrict__ out) {
    __shared__ float red[8][HIDDEN];   // 4KB
    int g = blockIdx.x;
    int t = threadIdx.x;
    int lane = t & 31;
    int grp = t >> 5;  // 0..7
    // range of graph g in sorted batch: [lower_bound(g), lower_bound(g+1))
    int lo = 0, hi = N_NODES;
    while (lo < hi) { int mid = (lo + hi) >> 1; if (batch[mid] < g) lo = mid + 1; else hi = mid; }
    int start = lo;
    hi = N_NODES;
    while (lo < hi) { int mid = (lo + hi) >> 1; if (batch[mid] < g + 1) lo = mid + 1; else hi = mid; }
    int end = lo;
    float4 acc = make_float4(0.f, 0.f, 0.f, 0.f);
    for (int n = start + grp; n < end; n += 8) {
        float4 v = *(const float4*)(h + (size_t)n * HIDDEN + lane * 4);
        acc.x += v.x; acc.y += v.y; acc.z += v.z; acc.w += v.w;
    }
    *(float4*)&red[grp][lane * 4] = acc;
    __syncthreads();
    if (t < HIDDEN) {
        float s = 0.f;
        #pragma unroll
        for (int i = 0; i < 8; ++i) s += red[i][t];
        float ic = 1.0f / fmaxf((float)(end - start), 1.0f);
        red[0][t] = s * ic;   // pooled[g][t]
    }
    __syncthreads();
    if (t < 64) {
        float p0 = red[0][t], p1 = red[0][t + 64];
        float dm = p0 * W_mem[t] + p1 * W_mem[t + 64];
        float dtv = p0 * W_time[t] + p1 * W_time[t + 64];
        #pragma unroll
        for (int m = 32; m >= 1; m >>= 1) {
            dm += __shfl_xor(dm, m, 64);
            dtv += __shfl_xor(dtv, m, 64);
        }
        if (t == 0) {
            out[g] = dm + b_mem[0];
            out[N_GRAPHS + g] = dtv + b_time[0];
        }
    }
}

extern "C" void kernel_launch(void* const* d_in, const int* in_sizes, int n_in,
                              void* d_out, int out_size, void* d_ws, size_t ws_size,
                              hipStream_t stream) {
    const float* x      = (const float*)d_in[0];
    const int*   edge   = (const int*)d_in[1];
    const int*   batch  = (const int*)d_in[2];
    const float* W_op   = (const float*)d_in[3];
    const float* b_op   = (const float*)d_in[4];
    const float* W_l    = (const float*)d_in[5];
    const float* b_l    = (const float*)d_in[6];
    const float* W_r    = (const float*)d_in[7];
    const float* gamma_ = (const float*)d_in[8];
    const float* beta_  = (const float*)d_in[9];
    const float* W_mem  = (const float*)d_in[10];
    const float* b_mem  = (const float*)d_in[11];
    const float* W_time = (const float*)d_in[12];
    const float* b_time = (const float*)d_in[13];
    const int* src = edge;
    const int* dst = edge + N_EDGES;

    char* ws = (char*)d_ws;
    const size_t hbytes = (size_t)N_NODES * HIDDEN * sizeof(float);  // 51.2MB
    float* h       = (float*)ws;
    float* agg     = (float*)(ws + hbytes);
    char*  p       = ws + 2 * hbytes;
    int*   degi    = (int*)p;                 p += (size_t)N_NODES * 4;
    int*   offsets = (int*)p;                 p += (size_t)N_NODES * 4;
    int*   cursor  = (int*)p;                 p += (size_t)N_NODES * 4;
    int*   csr     = (int*)p;                 p += (size_t)N_EDGES * 4;
    int*   bsum    = (int*)p;                 p += 2048;
    int*   boff    = (int*)p;                 p += 2048;

    // zero degree counters (ws is re-poisoned 0xAA before every call)
    hipMemsetAsync(degi, 0, (size_t)N_NODES * 4, stream);

    // CSR build
    deg_int_kernel<<<(N_EDGES + 255) / 256, 256, 0, stream>>>(dst, degi);
    scan_block_sums<<<NBLK_SCAN, 256, 0, stream>>>(degi, bsum);
    scan_partials<<<1, 512, 0, stream>>>(bsum, boff);
    scan_final<<<NBLK_SCAN, 256, 0, stream>>>(degi, boff, offsets, cursor);
    fill_csr<<<(N_EDGES + 255) / 256, 256, 0, stream>>>(src, dst, cursor, csr);

    // input projection
    proj_kernel<<<(N_NODES + 63) / 64, 256, 0, stream>>>(x, W_op, b_op, h);

    // layers
    for (int layer = 0; layer < 2; ++layer) {
        gather_kernel<<<(int)(((size_t)N_NODES * 32 + 255) / 256), 256, 0, stream>>>(
            h, csr, offsets, degi, agg);
        layer_kernel<<<(N_NODES + BM - 1) / BM, 256, 0, stream>>>(
            agg, W_l, b_l, W_r, gamma_, beta_, h);
    }

    // fused pooling + heads (no atomics: batch is sorted, binary-search ranges)
    pool_head_kernel<<<N_GRAPHS, 256, 0, stream>>>(h, batch, W_mem, b_mem, W_time, b_time, (float*)d_out);
}

// Round 8
// 771.256 us; speedup vs baseline: 8.0261x; 1.0032x over previous
//
#include <hip/hip_runtime.h>
#include <hip/hip_bf16.h>
#include <math.h>

#define N_NODES 100000
#define N_EDGES 1600000
#define N_FEAT 32
#define HIDDEN 128
#define N_GRAPHS 256
#define LN_EPS 1e-5f
#define BM 64
#define BK 32
#define NBLK_SCAN ((N_NODES + 255) / 256)   // 391

// ---------------- int degree over dst ----------------
__global__ __launch_bounds__(256) void deg_int_kernel(const int* __restrict__ dst,
                                                      int* __restrict__ degi) {
    int e = blockIdx.x * blockDim.x + threadIdx.x;
    if (e < N_EDGES) atomicAdd(&degi[dst[e]], 1);
}

// ---------------- scan step 1: per-block sums ----------------
__global__ __launch_bounds__(256) void scan_block_sums(const int* __restrict__ degi,
                                                       int* __restrict__ bsum) {
    __shared__ int red[256];
    int t = threadIdx.x;
    int i = blockIdx.x * 256 + t;
    red[t] = (i < N_NODES) ? degi[i] : 0;
    __syncthreads();
    #pragma unroll
    for (int off = 128; off > 0; off >>= 1) {
        if (t < off) red[t] += red[t + off];
        __syncthreads();
    }
    if (t == 0) bsum[blockIdx.x] = red[0];
}

// ---------------- scan step 2: exclusive scan of block sums (1 block) ----------------
__global__ __launch_bounds__(512) void scan_partials(const int* __restrict__ bsum,
                                                     int* __restrict__ boff) {
    __shared__ int s[512];
    int t = threadIdx.x;
    int v = (t < NBLK_SCAN) ? bsum[t] : 0;
    s[t] = v;
    __syncthreads();
    for (int off = 1; off < 512; off <<= 1) {
        int x = s[t];
        if (t >= off) x += s[t - off];
        __syncthreads();
        s[t] = x;
        __syncthreads();
    }
    if (t < NBLK_SCAN) boff[t] = s[t] - v;   // exclusive
}

// ---------------- scan step 3: per-element exclusive offsets + cursor copy ----------------
__global__ __launch_bounds__(256) void scan_final(const int* __restrict__ degi,
                                                  const int* __restrict__ boff,
                                                  int* __restrict__ offsets,
                                                  int* __restrict__ cursor) {
    __shared__ int s[256];
    int t = threadIdx.x;
    int i = blockIdx.x * 256 + t;
    int v = (i < N_NODES) ? degi[i] : 0;
    s[t] = v;
    __syncthreads();
    for (int off = 1; off < 256; off <<= 1) {
        int x = s[t];
        if (t >= off) x += s[t - off];
        __syncthreads();
        s[t] = x;
        __syncthreads();
    }
    if (i < N_NODES) {
        int ex = s[t] - v + boff[blockIdx.x];
        offsets[i] = ex;
        cursor[i] = ex;
    }
}

// ---------------- CSR fill: csr[slot] = src, bucketed by dst ----------------
// atomicExch instead of plain store: scattered 4B stores cost a full 64B
// dirty-line eviction each (measured 105.8MB HBM write for a 6.4MB buffer);
// the atomic path writes 16B sectors at the L3 atomic units (measured 16B/op
// in round 2) and avoids line bounce between non-coherent XCD L2s.
__global__ __launch_bounds__(256) void fill_csr(const int* __restrict__ src,
                                                const int* __restrict__ dst,
                                                int* __restrict__ cursor,
                                                int* __restrict__ csr) {
    int e = blockIdx.x * blockDim.x + threadIdx.x;
    if (e < N_EDGES) {
        int pos = atomicAdd(&cursor[dst[e]], 1);
        atomicExch(&csr[pos], src[e]);
    }
}

// ---------------- gather: agg[n] = mean over neighbors of h[src] ----------------
// cursor_end[n] == offsets[n] + deg[n] after fill_csr, so deg = end - start.
__global__ __launch_bounds__(256) void gather_kernel(const float* __restrict__ h,
                                                     const int* __restrict__ csr,
                                                     const int* __restrict__ offsets,
                                                     const int* __restrict__ cursor_end,
                                                     float* __restrict__ agg) {
    int node = (int)(((size_t)blockIdx.x * blockDim.x + threadIdx.x) >> 5);
    int lane = threadIdx.x & 31;
    if (node >= N_NODES) return;
    int st = offsets[node];
    int en = cursor_end[node];
    int dn = en - st;
    float4 a0 = make_float4(0.f, 0.f, 0.f, 0.f);
    float4 a1 = make_float4(0.f, 0.f, 0.f, 0.f);
    float4 a2 = make_float4(0.f, 0.f, 0.f, 0.f);
    float4 a3 = make_float4(0.f, 0.f, 0.f, 0.f);
    int i = st;
    for (; i + 4 <= en; i += 4) {
        int s0 = csr[i], s1 = csr[i + 1], s2 = csr[i + 2], s3 = csr[i + 3];
        float4 v0 = *(const float4*)(h + (size_t)s0 * HIDDEN + lane * 4);
        float4 v1 = *(const float4*)(h + (size_t)s1 * HIDDEN + lane * 4);
        float4 v2 = *(const float4*)(h + (size_t)s2 * HIDDEN + lane * 4);
        float4 v3 = *(const float4*)(h + (size_t)s3 * HIDDEN + lane * 4);
        a0.x += v0.x; a0.y += v0.y; a0.z += v0.z; a0.w += v0.w;
        a1.x += v1.x; a1.y += v1.y; a1.z += v1.z; a1.w += v1.w;
        a2.x += v2.x; a2.y += v2.y; a2.z += v2.z; a2.w += v2.w;
        a3.x += v3.x; a3.y += v3.y; a3.z += v3.z; a3.w += v3.w;
    }
    for (; i < en; ++i) {
        int s0 = csr[i];
        float4 v0 = *(const float4*)(h + (size_t)s0 * HIDDEN + lane * 4);
        a0.x += v0.x; a0.y += v0.y; a0.z += v0.z; a0.w += v0.w;
    }
    float inv = 1.0f / fmaxf((float)dn, 1.0f);
    float4 r;
    r.x = ((a0.x + a1.x) + (a2.x + a3.x)) * inv;
    r.y = ((a0.y + a1.y) + (a2.y + a3.y)) * inv;
    r.z = ((a0.z + a1.z) + (a2.z + a3.z)) * inv;
    r.w = ((a0.w + a1.w) + (a2.w + a3.w)) * inv;
    *(float4*)(agg + (size_t)node * HIDDEN + lane * 4) = r;
}

// ---------------- input projection: h = x @ W_op + b_op ----------------
__global__ __launch_bounds__(256) void proj_kernel(const float* __restrict__ x,
                                                   const float* __restrict__ W,
                                                   const float* __restrict__ b,
                                                   float* __restrict__ h) {
    __shared__ float ws[N_FEAT][HIDDEN];   // 16KB
    __shared__ float bs[HIDDEN];
    __shared__ float xs[64][N_FEAT];       // 8KB
    int t = threadIdx.x;
    #pragma unroll
    for (int i = 0; i < 4; ++i)
        ((float4*)&ws[0][0])[t + i * 256] = ((const float4*)W)[t + i * 256];
    if (t < 32) ((float4*)bs)[t] = ((const float4*)b)[t];
    int base = blockIdx.x * 64;
    #pragma unroll
    for (int i = 0; i < 2; ++i) {
        int f4 = t + i * 256;
        int node = base + (f4 >> 3);
        float4 v = make_float4(0.f, 0.f, 0.f, 0.f);
        if (node < N_NODES) v = ((const float4*)x)[(size_t)node * 8 + (f4 & 7)];
        ((float4*)&xs[0][0])[f4] = v;
    }
    __syncthreads();
    int c0 = (t & 31) * 4;
    int nslot = t >> 5;  // 0..7
    for (int it = 0; it < 8; ++it) {
        int nl = nslot + it * 8;
        int node = base + nl;
        float acc0 = bs[c0], acc1 = bs[c0 + 1], acc2 = bs[c0 + 2], acc3 = bs[c0 + 3];
        #pragma unroll
        for (int k = 0; k < N_FEAT; ++k) {
            float a = xs[nl][k];
            float4 w = *(const float4*)&ws[k][c0];
            acc0 += a * w.x; acc1 += a * w.y; acc2 += a * w.z; acc3 += a * w.w;
        }
        if (node < N_NODES)
            *(float4*)&h[(size_t)node * HIDDEN + c0] = make_float4(acc0, acc1, acc2, acc3);
    }
}

// ---------------- fused layer: h = LN(ELU(agg@W_l + b_l + h@W_r)) ----------------
__global__ __launch_bounds__(256) void layer_kernel(const float* __restrict__ agg,
                                                    const float* __restrict__ W_l,
                                                    const float* __restrict__ b_l,
                                                    const float* __restrict__ W_r,
                                                    const float* __restrict__ gamma_,
                                                    const float* __restrict__ beta_,
                                                    float* __restrict__ h) {
    __shared__ float a_s[BK][BM + 4];     // 8.5KB, K-major so M is contiguous
    __shared__ float b_s[BK][HIDDEN];     // 16KB
    int t = threadIdx.x;
    int row0 = blockIdx.x * BM;
    int tn = t & 31;   // col group: cols tn*4..tn*4+3
    int tm = t >> 5;   // row group: rows tm*8..tm*8+7
    int c0 = tn * 4;
    float acc[8][4] = {};
    // K = 256: tiles 0..3 = agg vs W_l, 4..7 = h vs W_r
    for (int kt = 0; kt < 8; ++kt) {
        const float* A = (kt < 4) ? agg : h;
        const float* W = (kt < 4) ? W_l : W_r;
        int kbase = (kt & 3) * BK;
        // A tile: 64 rows x 32 k, each thread 2 float4 (transposed store)
        {
            int m = t >> 3;
            int kq = (t & 7) * 4;
            #pragma unroll
            for (int half = 0; half < 2; ++half) {
                int mm = m + half * 32;
                int node = row0 + mm;
                float4 v = make_float4(0.f, 0.f, 0.f, 0.f);
                if (node < N_NODES)
                    v = *(const float4*)(A + (size_t)node * HIDDEN + kbase + kq);
                a_s[kq + 0][mm] = v.x; a_s[kq + 1][mm] = v.y;
                a_s[kq + 2][mm] = v.z; a_s[kq + 3][mm] = v.w;
            }
        }
        // B tile: 32 k x 128 cols, each thread 4 float4
        {
            int kk = t >> 5;
            int cc = (t & 31) * 4;
            #pragma unroll
            for (int i = 0; i < 4; ++i) {
                int k = kk + i * 8;
                *(float4*)&b_s[k][cc] = *(const float4*)(W + (size_t)(kbase + k) * HIDDEN + cc);
            }
        }
        __syncthreads();
        #pragma unroll 8
        for (int k = 0; k < BK; ++k) {
            float4 av0 = *(const float4*)&a_s[k][tm * 8];
            float4 av1 = *(const float4*)&a_s[k][tm * 8 + 4];
            float4 bv = *(const float4*)&b_s[k][c0];
            float av[8] = {av0.x, av0.y, av0.z, av0.w, av1.x, av1.y, av1.z, av1.w};
            #pragma unroll
            for (int r = 0; r < 8; ++r) {
                acc[r][0] += av[r] * bv.x; acc[r][1] += av[r] * bv.y;
                acc[r][2] += av[r] * bv.z; acc[r][3] += av[r] * bv.w;
            }
        }
        __syncthreads();
    }
    // epilogue: +b_l, ELU, LayerNorm (row = 32 lanes of same tm), in-place write
    float4 blv = *(const float4*)&b_l[c0];
    float4 gav = *(const float4*)&gamma_[c0];
    float4 bev = *(const float4*)&beta_[c0];
    float bl[4] = {blv.x, blv.y, blv.z, blv.w};
    float ga[4] = {gav.x, gav.y, gav.z, gav.w};
    float be[4] = {bev.x, bev.y, bev.z, bev.w};
    const float inv128 = 1.0f / 128.0f;
    #pragma unroll
    for (int r = 0; r < 8; ++r) {
        int node = row0 + tm * 8 + r;
        float v[4];
        float s = 0.f, sq = 0.f;
        #pragma unroll
        for (int j = 0; j < 4; ++j) {
            float xv = acc[r][j] + bl[j];
            xv = (xv > 0.f) ? xv : expm1f(xv);
            v[j] = xv; s += xv; sq += xv * xv;
        }
        #pragma unroll
        for (int m = 16; m >= 1; m >>= 1) {
            s += __shfl_xor(s, m, 64);
            sq += __shfl_xor(sq, m, 64);
        }
        float mu = s * inv128;
        float var = sq * inv128 - mu * mu;
        float rstd = rsqrtf(var + LN_EPS);
        if (node < N_NODES) {
            float4 o;
            o.x = (v[0] - mu) * rstd * ga[0] + be[0];
            o.y = (v[1] - mu) * rstd * ga[1] + be[1];
            o.z = (v[2] - mu) * rstd * ga[2] + be[2];
            o.w = (v[3] - mu) * rstd * ga[3] + be[3];
            *(float4*)&h[(size_t)node * HIDDEN + c0] = o;
        }
    }
}

// ---------------- fused pool + heads: one block per graph (batch is sorted) ----------------
__global__ __launch_bounds__(256) void pool_head_kernel(const float* __restrict__ h,
                                                        const int* __restrict__ batch,
                                                        const float* __restrict__ W_mem,
                                                        const float* __restrict__ b_mem,
                                                        const float* __restrict__ W_time,
                                                        const float* __restrict__ b_time,
                                                        float* __restrict__ out) {
    __shared__ float red[8][HIDDEN];   // 4KB
    int g = blockIdx.x;
    int t = threadIdx.x;
    int lane = t & 31;
    int grp = t >> 5;  // 0..7
    // range of graph g in sorted batch: [lower_bound(g), lower_bound(g+1))
    int lo = 0, hi = N_NODES;
    while (lo < hi) { int mid = (lo + hi) >> 1; if (batch[mid] < g) lo = mid + 1; else hi = mid; }
    int start = lo;
    hi = N_NODES;
    while (lo < hi) { int mid = (lo + hi) >> 1; if (batch[mid] < g + 1) lo = mid + 1; else hi = mid; }
    int end = lo;
    float4 acc = make_float4(0.f, 0.f, 0.f, 0.f);
    for (int n = start + grp; n < end; n += 8) {
        float4 v = *(const float4*)(h + (size_t)n * HIDDEN + lane * 4);
        acc.x += v.x; acc.y += v.y; acc.z += v.z; acc.w += v.w;
    }
    *(float4*)&red[grp][lane * 4] = acc;
    __syncthreads();
    if (t < HIDDEN) {
        float s = 0.f;
        #pragma unroll
        for (int i = 0; i < 8; ++i) s += red[i][t];
        float ic = 1.0f / fmaxf((float)(end - start), 1.0f);
        red[0][t] = s * ic;   // pooled[g][t]
    }
    __syncthreads();
    if (t < 64) {
        float p0 = red[0][t], p1 = red[0][t + 64];
        float dm = p0 * W_mem[t] + p1 * W_mem[t + 64];
        float dtv = p0 * W_time[t] + p1 * W_time[t + 64];
        #pragma unroll
        for (int m = 32; m >= 1; m >>= 1) {
            dm += __shfl_xor(dm, m, 64);
            dtv += __shfl_xor(dtv, m, 64);
        }
        if (t == 0) {
            out[g] = dm + b_mem[0];
            out[N_GRAPHS + g] = dtv + b_time[0];
        }
    }
}

extern "C" void kernel_launch(void* const* d_in, const int* in_sizes, int n_in,
                              void* d_out, int out_size, void* d_ws, size_t ws_size,
                              hipStream_t stream) {
    const float* x      = (const float*)d_in[0];
    const int*   edge   = (const int*)d_in[1];
    const int*   batch  = (const int*)d_in[2];
    const float* W_op   = (const float*)d_in[3];
    const float* b_op   = (const float*)d_in[4];
    const float* W_l    = (const float*)d_in[5];
    const float* b_l    = (const float*)d_in[6];
    const float* W_r    = (const float*)d_in[7];
    const float* gamma_ = (const float*)d_in[8];
    const float* beta_  = (const float*)d_in[9];
    const float* W_mem  = (const float*)d_in[10];
    const float* b_mem  = (const float*)d_in[11];
    const float* W_time = (const float*)d_in[12];
    const float* b_time = (const float*)d_in[13];
    const int* src = edge;
    const int* dst = edge + N_EDGES;

    char* ws = (char*)d_ws;
    const size_t hbytes = (size_t)N_NODES * HIDDEN * sizeof(float);  // 51.2MB
    float* h       = (float*)ws;
    float* agg     = (float*)(ws + hbytes);
    char*  p       = ws + 2 * hbytes;
    int*   degi    = (int*)p;                 p += (size_t)N_NODES * 4;
    int*   offsets = (int*)p;                 p += (size_t)N_NODES * 4;
    int*   cursor  = (int*)p;                 p += (size_t)N_NODES * 4;
    int*   csr     = (int*)p;                 p += (size_t)N_EDGES * 4;
    int*   bsum    = (int*)p;                 p += 2048;
    int*   boff    = (int*)p;                 p += 2048;

    // zero degree counters (ws is re-poisoned 0xAA before every call)
    hipMemsetAsync(degi, 0, (size_t)N_NODES * 4, stream);

    // CSR build
    deg_int_kernel<<<(N_EDGES + 255) / 256, 256, 0, stream>>>(dst, degi);
    scan_block_sums<<<NBLK_SCAN, 256, 0, stream>>>(degi, bsum);
    scan_partials<<<1, 512, 0, stream>>>(bsum, boff);
    scan_final<<<NBLK_SCAN, 256, 0, stream>>>(degi, boff, offsets, cursor);
    fill_csr<<<(N_EDGES + 255) / 256, 256, 0, stream>>>(src, dst, cursor, csr);

    // input projection
    proj_kernel<<<(N_NODES + 63) / 64, 256, 0, stream>>>(x, W_op, b_op, h);

    // layers (cursor now holds end offsets == offsets + deg)
    for (int layer = 0; layer < 2; ++layer) {
        gather_kernel<<<(int)(((size_t)N_NODES * 32 + 255) / 256), 256, 0, stream>>>(
            h, csr, offsets, cursor, agg);
        layer_kernel<<<(N_NODES + BM - 1) / BM, 256, 0, stream>>>(
            agg, W_l, b_l, W_r, gamma_, beta_, h);
    }

    // fused pooling + heads (no atomics: batch is sorted, binary-search ranges)
    pool_head_kernel<<<N_GRAPHS, 256, 0, stream>>>(h, batch, W_mem, b_mem, W_time, b_time, (float*)d_out);
}

// Round 10
// 758.923 us; speedup vs baseline: 8.1566x; 1.0162x over previous
//
#include <hip/hip_runtime.h>
#include <hip/hip_bf16.h>
#include <math.h>

#define N_NODES 100000
#define N_EDGES 1600000
#define N_FEAT 32
#define HIDDEN 128
#define N_GRAPHS 256
#define LN_EPS 1e-5f
#define BM 64
#define BK 32
#define NBLK_SCAN ((N_NODES + 255) / 256)   // 391

// CSR-build binning parameters
#define BSHIFT 10
#define NBUCK 98                            // buckets of 1024 nodes: 99999>>10 = 97
#define EPB 3840                            // edges per bin block (15 per thread)
#define NBIN ((N_EDGES + EPB - 1) / EPB)    // 417

// ---------------- int degree over dst ----------------
__global__ __launch_bounds__(256) void deg_int_kernel(const int* __restrict__ dst,
                                                      int* __restrict__ degi) {
    int e = blockIdx.x * blockDim.x + threadIdx.x;
    if (e < N_EDGES) atomicAdd(&degi[dst[e]], 1);
}

// ---------------- scan step 1: per-block sums ----------------
__global__ __launch_bounds__(256) void scan_block_sums(const int* __restrict__ degi,
                                                       int* __restrict__ bsum) {
    __shared__ int red[256];
    int t = threadIdx.x;
    int i = blockIdx.x * 256 + t;
    red[t] = (i < N_NODES) ? degi[i] : 0;
    __syncthreads();
    #pragma unroll
    for (int off = 128; off > 0; off >>= 1) {
        if (t < off) red[t] += red[t + off];
        __syncthreads();
    }
    if (t == 0) bsum[blockIdx.x] = red[0];
}

// ---------------- scan step 2: exclusive scan of block sums (1 block) ----------------
__global__ __launch_bounds__(512) void scan_partials(const int* __restrict__ bsum,
                                                     int* __restrict__ boff) {
    __shared__ int s[512];
    int t = threadIdx.x;
    int v = (t < NBLK_SCAN) ? bsum[t] : 0;
    s[t] = v;
    __syncthreads();
    for (int off = 1; off < 512; off <<= 1) {
        int x = s[t];
        if (t >= off) x += s[t - off];
        __syncthreads();
        s[t] = x;
        __syncthreads();
    }
    if (t < NBLK_SCAN) boff[t] = s[t] - v;   // exclusive
}

// ---------------- scan step 3: per-element exclusive offsets + cursor copy ----------------
__global__ __launch_bounds__(256) void scan_final(const int* __restrict__ degi,
                                                  const int* __restrict__ boff,
                                                  int* __restrict__ offsets,
                                                  int* __restrict__ cursor) {
    __shared__ int s[256];
    int t = threadIdx.x;
    int i = blockIdx.x * 256 + t;
    int v = (i < N_NODES) ? degi[i] : 0;
    s[t] = v;
    __syncthreads();
    for (int off = 1; off < 256; off <<= 1) {
        int x = s[t];
        if (t >= off) x += s[t - off];
        __syncthreads();
        s[t] = x;
        __syncthreads();
    }
    if (i < N_NODES) {
        int ex = s[t] - v + boff[blockIdx.x];
        offsets[i] = ex;
        cursor[i] = ex;
    }
}

// ---------------- bucket histogram (dst>>10) ----------------
__global__ __launch_bounds__(256) void hist_bucket(const int* __restrict__ dst,
                                                   int* __restrict__ histg) {
    __shared__ int h[NBUCK];
    int t = threadIdx.x;
    if (t < NBUCK) h[t] = 0;
    __syncthreads();
    int base = blockIdx.x * EPB;
    #pragma unroll
    for (int i = 0; i < EPB / 256; ++i) {
        int e = base + i * 256 + t;
        if (e < N_EDGES) atomicAdd(&h[dst[e] >> BSHIFT], 1);
    }
    __syncthreads();
    if (t < NBUCK && h[t]) atomicAdd(&histg[t], h[t]);
}

// ---------------- bucket base scan (1 block) ----------------
__global__ __launch_bounds__(128) void scan_bucket(const int* __restrict__ histg,
                                                   int* __restrict__ bbase,
                                                   int* __restrict__ bcur) {
    __shared__ int sb[128];
    int t = threadIdx.x;
    int v = (t < NBUCK) ? histg[t] : 0;
    sb[t] = v;
    __syncthreads();
    for (int off = 1; off < 128; off <<= 1) {
        int x = sb[t];
        if (t >= off) x += sb[t - off];
        __syncthreads();
        sb[t] = x;
        __syncthreads();
    }
    if (t < NBUCK) { bbase[t] = sb[t] - v; bcur[t] = sb[t] - v; }
    if (t == NBUCK - 1) bbase[NBUCK] = sb[t];
}

// ---------------- bin pass: LDS counting-sort edges by bucket, write stash ----------------
// Scattered 4B stores cost a full 64B dirty-line eviction each (measured
// 99.9MB HBM write for 6.4MB of csr in r8; atomicExch identical — it's the
// cross-XCD line bouncing, not the op type). So: sort block's edges by
// bucket in LDS, write contiguous bucket-runs (~39 pairs = ~312B) to a
// bucket-major stash via chunk reservations -> mostly full-line writes.
__global__ __launch_bounds__(256) void bin_pass(const int* __restrict__ src,
                                                const int* __restrict__ dst,
                                                int* __restrict__ bcur,
                                                uint2* __restrict__ stash) {
    __shared__ int srcL[EPB];
    __shared__ int dstL[EPB];
    __shared__ int hist[NBUCK], lex[NBUCK], lcur[NBUCK], gbase[NBUCK];
    __shared__ int sb[128];
    int t = threadIdx.x;
    if (t < NBUCK) hist[t] = 0;
    __syncthreads();
    int base = blockIdx.x * EPB;
    #pragma unroll
    for (int i = 0; i < EPB / 256; ++i) {
        int e = base + i * 256 + t;
        if (e < N_EDGES) atomicAdd(&hist[dst[e] >> BSHIFT], 1);
    }
    __syncthreads();
    // exclusive scan of hist into lex (padded Hillis-Steele over 128)
    {
        int v = (t < NBUCK) ? hist[t] : 0;
        if (t < 128) sb[t] = v;
        __syncthreads();
        for (int off = 1; off < 128; off <<= 1) {
            int x = 0;
            if (t < 128) { x = sb[t]; if (t >= off) x += sb[t - off]; }
            __syncthreads();
            if (t < 128) sb[t] = x;
            __syncthreads();
        }
        if (t < NBUCK) {
            int ex = sb[t] - hist[t];
            lex[t] = ex; lcur[t] = ex;
            gbase[t] = atomicAdd(&bcur[t], hist[t]);   // reserve global chunk
        }
    }
    __syncthreads();
    // scatter into LDS, bucket-grouped
    #pragma unroll
    for (int i = 0; i < EPB / 256; ++i) {
        int e = base + i * 256 + t;
        if (e < N_EDGES) {
            int d = dst[e];
            int p = atomicAdd(&lcur[d >> BSHIFT], 1);
            dstL[p] = d; srcL[p] = src[e];
        }
    }
    __syncthreads();
    // coalesced copy-out: output position -> bucket via binary search over lex
    int n_e = min(EPB, N_EDGES - base);
    #pragma unroll
    for (int i = 0; i < EPB / 256; ++i) {
        int idx = i * 256 + t;
        if (idx < n_e) {
            int lo = 0, hi = NBUCK - 1;
            while (lo < hi) { int mid = (lo + hi + 1) >> 1; if (lex[mid] <= idx) lo = mid; else hi = mid - 1; }
            int g = gbase[lo] + (idx - lex[lo]);
            stash[g] = make_uint2((unsigned)dstL[idx], (unsigned)srcL[idx]);
        }
    }
}

// ---------------- fill pass: one block per bucket, scatter into csr ----------------
// Target csr region per block is ~65KB touched by a single block (single XCD,
// temporally tight) -> each line dirtied once, written back once.
__global__ __launch_bounds__(256) void fill_pass(const uint2* __restrict__ stash,
                                                 const int* __restrict__ bbase,
                                                 int* __restrict__ cursor,
                                                 int* __restrict__ csr) {
    int k = blockIdx.x;
    int beg = bbase[k], end = bbase[k + 1];
    for (int i = beg + threadIdx.x; i < end; i += 256) {
        uint2 p = stash[i];
        int pos = atomicAdd(&cursor[p.x], 1);
        csr[pos] = (int)p.y;
    }
}

// ---------------- gather: agg[n] = mean over neighbors of h[src] ----------------
// cursor_end[n] == offsets[n] + deg[n] after fill_pass, so deg = end - start.
__global__ __launch_bounds__(256) void gather_kernel(const float* __restrict__ h,
                                                     const int* __restrict__ csr,
                                                     const int* __restrict__ offsets,
                                                     const int* __restrict__ cursor_end,
                                                     float* __restrict__ agg) {
    int node = (int)(((size_t)blockIdx.x * blockDim.x + threadIdx.x) >> 5);
    int lane = threadIdx.x & 31;
    if (node >= N_NODES) return;
    int st = offsets[node];
    int en = cursor_end[node];
    int dn = en - st;
    float4 a0 = make_float4(0.f, 0.f, 0.f, 0.f);
    float4 a1 = make_float4(0.f, 0.f, 0.f, 0.f);
    float4 a2 = make_float4(0.f, 0.f, 0.f, 0.f);
    float4 a3 = make_float4(0.f, 0.f, 0.f, 0.f);
    int i = st;
    for (; i + 4 <= en; i += 4) {
        int s0 = csr[i], s1 = csr[i + 1], s2 = csr[i + 2], s3 = csr[i + 3];
        float4 v0 = *(const float4*)(h + (size_t)s0 * HIDDEN + lane * 4);
        float4 v1 = *(const float4*)(h + (size_t)s1 * HIDDEN + lane * 4);
        float4 v2 = *(const float4*)(h + (size_t)s2 * HIDDEN + lane * 4);
        float4 v3 = *(const float4*)(h + (size_t)s3 * HIDDEN + lane * 4);
        a0.x += v0.x; a0.y += v0.y; a0.z += v0.z; a0.w += v0.w;
        a1.x += v1.x; a1.y += v1.y; a1.z += v1.z; a1.w += v1.w;
        a2.x += v2.x; a2.y += v2.y; a2.z += v2.z; a2.w += v2.w;
        a3.x += v3.x; a3.y += v3.y; a3.z += v3.z; a3.w += v3.w;
    }
    for (; i < en; ++i) {
        int s0 = csr[i];
        float4 v0 = *(const float4*)(h + (size_t)s0 * HIDDEN + lane * 4);
        a0.x += v0.x; a0.y += v0.y; a0.z += v0.z; a0.w += v0.w;
    }
    float inv = 1.0f / fmaxf((float)dn, 1.0f);
    float4 r;
    r.x = ((a0.x + a1.x) + (a2.x + a3.x)) * inv;
    r.y = ((a0.y + a1.y) + (a2.y + a3.y)) * inv;
    r.z = ((a0.z + a1.z) + (a2.z + a3.z)) * inv;
    r.w = ((a0.w + a1.w) + (a2.w + a3.w)) * inv;
    *(float4*)(agg + (size_t)node * HIDDEN + lane * 4) = r;
}

// ---------------- input projection: h = x @ W_op + b_op ----------------
__global__ __launch_bounds__(256) void proj_kernel(const float* __restrict__ x,
                                                   const float* __restrict__ W,
                                                   const float* __restrict__ b,
                                                   float* __restrict__ h) {
    __shared__ float ws[N_FEAT][HIDDEN];   // 16KB
    __shared__ float bs[HIDDEN];
    __shared__ float xs[64][N_FEAT];       // 8KB
    int t = threadIdx.x;
    #pragma unroll
    for (int i = 0; i < 4; ++i)
        ((float4*)&ws[0][0])[t + i * 256] = ((const float4*)W)[t + i * 256];
    if (t < 32) ((float4*)bs)[t] = ((const float4*)b)[t];
    int base = blockIdx.x * 64;
    #pragma unroll
    for (int i = 0; i < 2; ++i) {
        int f4 = t + i * 256;
        int node = base + (f4 >> 3);
        float4 v = make_float4(0.f, 0.f, 0.f, 0.f);
        if (node < N_NODES) v = ((const float4*)x)[(size_t)node * 8 + (f4 & 7)];
        ((float4*)&xs[0][0])[f4] = v;
    }
    __syncthreads();
    int c0 = (t & 31) * 4;
    int nslot = t >> 5;  // 0..7
    for (int it = 0; it < 8; ++it) {
        int nl = nslot + it * 8;
        int node = base + nl;
        float acc0 = bs[c0], acc1 = bs[c0 + 1], acc2 = bs[c0 + 2], acc3 = bs[c0 + 3];
        #pragma unroll
        for (int k = 0; k < N_FEAT; ++k) {
            float a = xs[nl][k];
            float4 w = *(const float4*)&ws[k][c0];
            acc0 += a * w.x; acc1 += a * w.y; acc2 += a * w.z; acc3 += a * w.w;
        }
        if (node < N_NODES)
            *(float4*)&h[(size_t)node * HIDDEN + c0] = make_float4(acc0, acc1, acc2, acc3);
    }
}

// ---------------- fused layer: h = LN(ELU(agg@W_l + b_l + h@W_r)) ----------------
__global__ __launch_bounds__(256) void layer_kernel(const float* __restrict__ agg,
                                                    const float* __restrict__ W_l,
                                                    const float* __restrict__ b_l,
                                                    const float* __restrict__ W_r,
                                                    const float* __restrict__ gamma_,
                                                    const float* __restrict__ beta_,
                                                    float* __restrict__ h) {
    __shared__ float a_s[BK][BM + 4];     // 8.5KB, K-major so M is contiguous
    __shared__ float b_s[BK][HIDDEN];     // 16KB
    int t = threadIdx.x;
    int row0 = blockIdx.x * BM;
    int tn = t & 31;   // col group: cols tn*4..tn*4+3
    int tm = t >> 5;   // row group: rows tm*8..tm*8+7
    int c0 = tn * 4;
    float acc[8][4] = {};
    // K = 256: tiles 0..3 = agg vs W_l, 4..7 = h vs W_r
    for (int kt = 0; kt < 8; ++kt) {
        const float* A = (kt < 4) ? agg : h;
        const float* W = (kt < 4) ? W_l : W_r;
        int kbase = (kt & 3) * BK;
        // A tile: 64 rows x 32 k, each thread 2 float4 (transposed store)
        {
            int m = t >> 3;
            int kq = (t & 7) * 4;
            #pragma unroll
            for (int half = 0; half < 2; ++half) {
                int mm = m + half * 32;
                int node = row0 + mm;
                float4 v = make_float4(0.f, 0.f, 0.f, 0.f);
                if (node < N_NODES)
                    v = *(const float4*)(A + (size_t)node * HIDDEN + kbase + kq);
                a_s[kq + 0][mm] = v.x; a_s[kq + 1][mm] = v.y;
                a_s[kq + 2][mm] = v.z; a_s[kq + 3][mm] = v.w;
            }
        }
        // B tile: 32 k x 128 cols, each thread 4 float4
        {
            int kk = t >> 5;
            int cc = (t & 31) * 4;
            #pragma unroll
            for (int i = 0; i < 4; ++i) {
                int k = kk + i * 8;
                *(float4*)&b_s[k][cc] = *(const float4*)(W + (size_t)(kbase + k) * HIDDEN + cc);
            }
        }
        __syncthreads();
        #pragma unroll 8
        for (int k = 0; k < BK; ++k) {
            float4 av0 = *(const float4*)&a_s[k][tm * 8];
            float4 av1 = *(const float4*)&a_s[k][tm * 8 + 4];
            float4 bv = *(const float4*)&b_s[k][c0];
            float av[8] = {av0.x, av0.y, av0.z, av0.w, av1.x, av1.y, av1.z, av1.w};
            #pragma unroll
            for (int r = 0; r < 8; ++r) {
                acc[r][0] += av[r] * bv.x; acc[r][1] += av[r] * bv.y;
                acc[r][2] += av[r] * bv.z; acc[r][3] += av[r] * bv.w;
            }
        }
        __syncthreads();
    }
    // epilogue: +b_l, ELU, LayerNorm (row = 32 lanes of same tm), in-place write
    float4 blv = *(const float4*)&b_l[c0];
    float4 gav = *(const float4*)&gamma_[c0];
    float4 bev = *(const float4*)&beta_[c0];
    float bl[4] = {blv.x, blv.y, blv.z, blv.w};
    float ga[4] = {gav.x, gav.y, gav.z, gav.w};
    float be[4] = {bev.x, bev.y, bev.z, bev.w};
    const float inv128 = 1.0f / 128.0f;
    #pragma unroll
    for (int r = 0; r < 8; ++r) {
        int node = row0 + tm * 8 + r;
        float v[4];
        float s = 0.f, sq = 0.f;
        #pragma unroll
        for (int j = 0; j < 4; ++j) {
            float xv = acc[r][j] + bl[j];
            xv = (xv > 0.f) ? xv : expm1f(xv);
            v[j] = xv; s += xv; sq += xv * xv;
        }
        #pragma unroll
        for (int m = 16; m >= 1; m >>= 1) {
            s += __shfl_xor(s, m, 64);
            sq += __shfl_xor(sq, m, 64);
        }
        float mu = s * inv128;
        float var = sq * inv128 - mu * mu;
        float rstd = rsqrtf(var + LN_EPS);
        if (node < N_NODES) {
            float4 o;
            o.x = (v[0] - mu) * rstd * ga[0] + be[0];
            o.y = (v[1] - mu) * rstd * ga[1] + be[1];
            o.z = (v[2] - mu) * rstd * ga[2] + be[2];
            o.w = (v[3] - mu) * rstd * ga[3] + be[3];
            *(float4*)&h[(size_t)node * HIDDEN + c0] = o;
        }
    }
}

// ---------------- fused pool + heads: one block per graph (batch is sorted) ----------------
__global__ __launch_bounds__(256) void pool_head_kernel(const float* __restrict__ h,
                                                        const int* __restrict__ batch,
                                                        const float* __restrict__ W_mem,
                                                        const float* __restrict__ b_mem,
                                                        const float* __restrict__ W_time,
                                                        const float* __restrict__ b_time,
                                                        float* __restrict__ out) {
    __shared__ float red[8][HIDDEN];   // 4KB
    int g = blockIdx.x;
    int t = threadIdx.x;
    int lane = t & 31;
    int grp = t >> 5;  // 0..7
    // range of graph g in sorted batch: [lower_bound(g), lower_bound(g+1))
    int lo = 0, hi = N_NODES;
    while (lo < hi) { int mid = (lo + hi) >> 1; if (batch[mid] < g) lo = mid + 1; else hi = mid; }
    int start = lo;
    hi = N_NODES;
    while (lo < hi) { int mid = (lo + hi) >> 1; if (batch[mid] < g + 1) lo = mid + 1; else hi = mid; }
    int end = lo;
    float4 acc = make_float4(0.f, 0.f, 0.f, 0.f);
    for (int n = start + grp; n < end; n += 8) {
        float4 v = *(const float4*)(h + (size_t)n * HIDDEN + lane * 4);
        acc.x += v.x; acc.y += v.y; acc.z += v.z; acc.w += v.w;
    }
    *(float4*)&red[grp][lane * 4] = acc;
    __syncthreads();
    if (t < HIDDEN) {
        float s = 0.f;
        #pragma unroll
        for (int i = 0; i < 8; ++i) s += red[i][t];
        float ic = 1.0f / fmaxf((float)(end - start), 1.0f);
        red[0][t] = s * ic;   // pooled[g][t]
    }
    __syncthreads();
    if (t < 64) {
        float p0 = red[0][t], p1 = red[0][t + 64];
        float dm = p0 * W_mem[t] + p1 * W_mem[t + 64];
        float dtv = p0 * W_time[t] + p1 * W_time[t + 64];
        #pragma unroll
        for (int m = 32; m >= 1; m >>= 1) {
            dm += __shfl_xor(dm, m, 64);
            dtv += __shfl_xor(dtv, m, 64);
        }
        if (t == 0) {
            out[g] = dm + b_mem[0];
            out[N_GRAPHS + g] = dtv + b_time[0];
        }
    }
}

extern "C" void kernel_launch(void* const* d_in, const int* in_sizes, int n_in,
                              void* d_out, int out_size, void* d_ws, size_t ws_size,
                              hipStream_t stream) {
    const float* x      = (const float*)d_in[0];
    const int*   edge   = (const int*)d_in[1];
    const int*   batch  = (const int*)d_in[2];
    const float* W_op   = (const float*)d_in[3];
    const float* b_op   = (const float*)d_in[4];
    const float* W_l    = (const float*)d_in[5];
    const float* b_l    = (const float*)d_in[6];
    const float* W_r    = (const float*)d_in[7];
    const float* gamma_ = (const float*)d_in[8];
    const float* beta_  = (const float*)d_in[9];
    const float* W_mem  = (const float*)d_in[10];
    const float* b_mem  = (const float*)d_in[11];
    const float* W_time = (const float*)d_in[12];
    const float* b_time = (const float*)d_in[13];
    const int* src = edge;
    const int* dst = edge + N_EDGES;

    char* ws = (char*)d_ws;
    const size_t hbytes = (size_t)N_NODES * HIDDEN * sizeof(float);  // 51.2MB
    float* h       = (float*)ws;
    float* agg     = (float*)(ws + hbytes);
    char*  p       = ws + 2 * hbytes;
    int*   degi    = (int*)p;                 p += (size_t)N_NODES * 4;
    int*   offsets = (int*)p;                 p += (size_t)N_NODES * 4;
    int*   cursor  = (int*)p;                 p += (size_t)N_NODES * 4;
    int*   csr     = (int*)p;                 p += (size_t)N_EDGES * 4;
    int*   bsum    = (int*)p;                 p += 2048;
    int*   boff    = (int*)p;                 p += 2048;
    int*   histg   = (int*)p;                 p += 512;
    int*   bbase   = (int*)p;                 p += 512;
    int*   bcur    = (int*)p;                 p += 512;
    // stash (1.6M uint2 = 12.8MB) aliases agg: agg is dead until first gather,
    // which runs only after fill_pass has consumed the stash.
    uint2* stash   = (uint2*)agg;

    // zero counters (ws is re-poisoned 0xAA before every call)
    hipMemsetAsync(degi, 0, (size_t)N_NODES * 4, stream);
    hipMemsetAsync(histg, 0, NBUCK * sizeof(int), stream);

    // per-node degree + offsets
    deg_int_kernel<<<(N_EDGES + 255) / 256, 256, 0, stream>>>(dst, degi);
    scan_block_sums<<<NBLK_SCAN, 256, 0, stream>>>(degi, bsum);
    scan_partials<<<1, 512, 0, stream>>>(bsum, boff);
    scan_final<<<NBLK_SCAN, 256, 0, stream>>>(degi, boff, offsets, cursor);

    // binned CSR build: hist -> bases -> LDS-sort to stash -> local scatter
    hist_bucket<<<NBIN, 256, 0, stream>>>(dst, histg);
    scan_bucket<<<1, 128, 0, stream>>>(histg, bbase, bcur);
    bin_pass<<<NBIN, 256, 0, stream>>>(src, dst, bcur, stash);
    fill_pass<<<NBUCK, 256, 0, stream>>>(stash, bbase, cursor, csr);

    // input projection
    proj_kernel<<<(N_NODES + 63) / 64, 256, 0, stream>>>(x, W_op, b_op, h);

    // layers (cursor now holds end offsets == offsets + deg)
    for (int layer = 0; layer < 2; ++layer) {
        gather_kernel<<<(int)(((size_t)N_NODES * 32 + 255) / 256), 256, 0, stream>>>(
            h, csr, offsets, cursor, agg);
        layer_kernel<<<(N_NODES + BM - 1) / BM, 256, 0, stream>>>(
            agg, W_l, b_l, W_r, gamma_, beta_, h);
    }

    // fused pooling + heads (no atomics: batch is sorted, binary-search ranges)
    pool_head_kernel<<<N_GRAPHS, 256, 0, stream>>>(h, batch, W_mem, b_mem, W_time, b_time, (float*)d_out);
}

// Round 11
// 548.041 us; speedup vs baseline: 11.2951x; 1.3848x over previous
//
#include <hip/hip_runtime.h>
#include <hip/hip_bf16.h>
#include <math.h>

#define N_NODES 100000
#define N_EDGES 1600000
#define N_FEAT 32
#define HIDDEN 128
#define N_GRAPHS 256
#define LN_EPS 1e-5f
#define NBLK_SCAN ((N_NODES + 255) / 256)   // 391

// CSR-build binning parameters
#define BSHIFT 10
#define NBUCK 98                            // buckets of 1024 nodes
#define EPB 3840                            // edges per bin block
#define NBIN ((N_EDGES + EPB - 1) / EPB)    // 417

// MFMA layer tile
#define LBM 128                             // rows per block (4 waves x 32)
#define AT_STRIDE 40                        // LDS row stride in ushorts (80B: 16B-aligned, 2-way-max bank alias)

typedef __attribute__((ext_vector_type(8))) short bf16x8;   // 8 bf16 = 4 VGPRs
typedef __attribute__((ext_vector_type(4))) float f32x4;    // MFMA accumulator

__device__ __forceinline__ float bf2f(unsigned short u) {
    return __uint_as_float(((unsigned int)u) << 16);
}
__device__ __forceinline__ unsigned short f2bf(float f) {
    unsigned int u = __float_as_uint(f);
    u += 0x7FFFu + ((u >> 16) & 1u);        // round-to-nearest-even
    return (unsigned short)(u >> 16);
}

// ---------------- int degree over dst ----------------
__global__ __launch_bounds__(256) void deg_int_kernel(const int* __restrict__ dst,
                                                      int* __restrict__ degi) {
    int e = blockIdx.x * blockDim.x + threadIdx.x;
    if (e < N_EDGES) atomicAdd(&degi[dst[e]], 1);
}

// ---------------- scan step 1 ----------------
__global__ __launch_bounds__(256) void scan_block_sums(const int* __restrict__ degi,
                                                       int* __restrict__ bsum) {
    __shared__ int red[256];
    int t = threadIdx.x;
    int i = blockIdx.x * 256 + t;
    red[t] = (i < N_NODES) ? degi[i] : 0;
    __syncthreads();
    #pragma unroll
    for (int off = 128; off > 0; off >>= 1) {
        if (t < off) red[t] += red[t + off];
        __syncthreads();
    }
    if (t == 0) bsum[blockIdx.x] = red[0];
}

// ---------------- scan step 2 ----------------
__global__ __launch_bounds__(512) void scan_partials(const int* __restrict__ bsum,
                                                     int* __restrict__ boff) {
    __shared__ int s[512];
    int t = threadIdx.x;
    int v = (t < NBLK_SCAN) ? bsum[t] : 0;
    s[t] = v;
    __syncthreads();
    for (int off = 1; off < 512; off <<= 1) {
        int x = s[t];
        if (t >= off) x += s[t - off];
        __syncthreads();
        s[t] = x;
        __syncthreads();
    }
    if (t < NBLK_SCAN) boff[t] = s[t] - v;
}

// ---------------- scan step 3 ----------------
__global__ __launch_bounds__(256) void scan_final(const int* __restrict__ degi,
                                                  const int* __restrict__ boff,
                                                  int* __restrict__ offsets,
                                                  int* __restrict__ cursor) {
    __shared__ int s[256];
    int t = threadIdx.x;
    int i = blockIdx.x * 256 + t;
    int v = (i < N_NODES) ? degi[i] : 0;
    s[t] = v;
    __syncthreads();
    for (int off = 1; off < 256; off <<= 1) {
        int x = s[t];
        if (t >= off) x += s[t - off];
        __syncthreads();
        s[t] = x;
        __syncthreads();
    }
    if (i < N_NODES) {
        int ex = s[t] - v + boff[blockIdx.x];
        offsets[i] = ex;
        cursor[i] = ex;
    }
}

// ---------------- bucket histogram ----------------
__global__ __launch_bounds__(256) void hist_bucket(const int* __restrict__ dst,
                                                   int* __restrict__ histg) {
    __shared__ int h[NBUCK];
    int t = threadIdx.x;
    if (t < NBUCK) h[t] = 0;
    __syncthreads();
    int base = blockIdx.x * EPB;
    #pragma unroll
    for (int i = 0; i < EPB / 256; ++i) {
        int e = base + i * 256 + t;
        if (e < N_EDGES) atomicAdd(&h[dst[e] >> BSHIFT], 1);
    }
    __syncthreads();
    if (t < NBUCK && h[t]) atomicAdd(&histg[t], h[t]);
}

// ---------------- bucket base scan ----------------
__global__ __launch_bounds__(128) void scan_bucket(const int* __restrict__ histg,
                                                   int* __restrict__ bbase,
                                                   int* __restrict__ bcur) {
    __shared__ int sb[128];
    int t = threadIdx.x;
    int v = (t < NBUCK) ? histg[t] : 0;
    sb[t] = v;
    __syncthreads();
    for (int off = 1; off < 128; off <<= 1) {
        int x = sb[t];
        if (t >= off) x += sb[t - off];
        __syncthreads();
        sb[t] = x;
        __syncthreads();
    }
    if (t < NBUCK) { bbase[t] = sb[t] - v; bcur[t] = sb[t] - v; }
    if (t == NBUCK - 1) bbase[NBUCK] = sb[t];
}

// ---------------- bin pass (locality-creating LDS counting sort) ----------------
__global__ __launch_bounds__(256) void bin_pass(const int* __restrict__ src,
                                                const int* __restrict__ dst,
                                                int* __restrict__ bcur,
                                                uint2* __restrict__ stash) {
    __shared__ int srcL[EPB];
    __shared__ int dstL[EPB];
    __shared__ int hist[NBUCK], lex[NBUCK], lcur[NBUCK], gbase[NBUCK];
    __shared__ int sb[128];
    int t = threadIdx.x;
    if (t < NBUCK) hist[t] = 0;
    __syncthreads();
    int base = blockIdx.x * EPB;
    #pragma unroll
    for (int i = 0; i < EPB / 256; ++i) {
        int e = base + i * 256 + t;
        if (e < N_EDGES) atomicAdd(&hist[dst[e] >> BSHIFT], 1);
    }
    __syncthreads();
    {
        int v = (t < NBUCK) ? hist[t] : 0;
        if (t < 128) sb[t] = v;
        __syncthreads();
        for (int off = 1; off < 128; off <<= 1) {
            int x = 0;
            if (t < 128) { x = sb[t]; if (t >= off) x += sb[t - off]; }
            __syncthreads();
            if (t < 128) sb[t] = x;
            __syncthreads();
        }
        if (t < NBUCK) {
            int ex = sb[t] - hist[t];
            lex[t] = ex; lcur[t] = ex;
            gbase[t] = atomicAdd(&bcur[t], hist[t]);
        }
    }
    __syncthreads();
    #pragma unroll
    for (int i = 0; i < EPB / 256; ++i) {
        int e = base + i * 256 + t;
        if (e < N_EDGES) {
            int d = dst[e];
            int p = atomicAdd(&lcur[d >> BSHIFT], 1);
            dstL[p] = d; srcL[p] = src[e];
        }
    }
    __syncthreads();
    int n_e = min(EPB, N_EDGES - base);
    #pragma unroll
    for (int i = 0; i < EPB / 256; ++i) {
        int idx = i * 256 + t;
        if (idx < n_e) {
            int lo = 0, hi = NBUCK - 1;
            while (lo < hi) { int mid = (lo + hi + 1) >> 1; if (lex[mid] <= idx) lo = mid; else hi = mid - 1; }
            int g = gbase[lo] + (idx - lex[lo]);
            stash[g] = make_uint2((unsigned)dstL[idx], (unsigned)srcL[idx]);
        }
    }
}

// ---------------- fill pass ----------------
__global__ __launch_bounds__(256) void fill_pass(const uint2* __restrict__ stash,
                                                 const int* __restrict__ bbase,
                                                 int* __restrict__ cursor,
                                                 int* __restrict__ csr) {
    int k = blockIdx.x;
    int beg = bbase[k], end = bbase[k + 1];
    for (int i = beg + threadIdx.x; i < end; i += 256) {
        uint2 p = stash[i];
        int pos = atomicAdd(&cursor[p.x], 1);
        csr[pos] = (int)p.y;
    }
}

// ---------------- weight prep: Wt[n][k] = bf16 of [W_l; W_r][k][n] ----------------
__global__ __launch_bounds__(256) void prep_w(const float* __restrict__ Wl,
                                              const float* __restrict__ Wr,
                                              unsigned short* __restrict__ Wt) {
    int idx = blockIdx.x * 256 + threadIdx.x;
    if (idx < HIDDEN * 2 * HIDDEN) {
        int n = idx >> 8, k = idx & 255;
        float v = (k < HIDDEN) ? Wl[k * HIDDEN + n] : Wr[(k - HIDDEN) * HIDDEN + n];
        Wt[n * 256 + k] = f2bf(v);
    }
}

// ---------------- input projection -> bf16 h ----------------
__global__ __launch_bounds__(256) void proj_kernel(const float* __restrict__ x,
                                                   const float* __restrict__ W,
                                                   const float* __restrict__ b,
                                                   unsigned short* __restrict__ hb) {
    __shared__ float ws[N_FEAT][HIDDEN];
    __shared__ float bs[HIDDEN];
    __shared__ float xs[64][N_FEAT];
    int t = threadIdx.x;
    #pragma unroll
    for (int i = 0; i < 4; ++i)
        ((float4*)&ws[0][0])[t + i * 256] = ((const float4*)W)[t + i * 256];
    if (t < 32) ((float4*)bs)[t] = ((const float4*)b)[t];
    int base = blockIdx.x * 64;
    #pragma unroll
    for (int i = 0; i < 2; ++i) {
        int f4 = t + i * 256;
        int node = base + (f4 >> 3);
        float4 v = make_float4(0.f, 0.f, 0.f, 0.f);
        if (node < N_NODES) v = ((const float4*)x)[(size_t)node * 8 + (f4 & 7)];
        ((float4*)&xs[0][0])[f4] = v;
    }
    __syncthreads();
    int c0 = (t & 31) * 4;
    int nslot = t >> 5;
    for (int it = 0; it < 8; ++it) {
        int nl = nslot + it * 8;
        int node = base + nl;
        float acc0 = bs[c0], acc1 = bs[c0 + 1], acc2 = bs[c0 + 2], acc3 = bs[c0 + 3];
        #pragma unroll
        for (int k = 0; k < N_FEAT; ++k) {
            float a = xs[nl][k];
            float4 w = *(const float4*)&ws[k][c0];
            acc0 += a * w.x; acc1 += a * w.y; acc2 += a * w.z; acc3 += a * w.w;
        }
        if (node < N_NODES) {
            ushort4 o;
            o.x = f2bf(acc0); o.y = f2bf(acc1); o.z = f2bf(acc2); o.w = f2bf(acc3);
            *(ushort4*)&hb[(size_t)node * HIDDEN + c0] = o;
        }
    }
}

// ---------------- gather (bf16 payload): agg_b[n] = mean of hb[src] ----------------
__global__ __launch_bounds__(256) void gather_kernel(const unsigned short* __restrict__ hb,
                                                     const int* __restrict__ csr,
                                                     const int* __restrict__ offsets,
                                                     const int* __restrict__ cursor_end,
                                                     unsigned short* __restrict__ aggb) {
    int node = (int)(((size_t)blockIdx.x * blockDim.x + threadIdx.x) >> 5);
    int lane = threadIdx.x & 31;
    if (node >= N_NODES) return;
    int st = offsets[node];
    int en = cursor_end[node];
    int dn = en - st;
    float a0[4] = {0.f, 0.f, 0.f, 0.f};
    float a1[4] = {0.f, 0.f, 0.f, 0.f};
    float a2[4] = {0.f, 0.f, 0.f, 0.f};
    float a3[4] = {0.f, 0.f, 0.f, 0.f};
    int i = st;
    for (; i + 4 <= en; i += 4) {
        int s0 = csr[i], s1 = csr[i + 1], s2 = csr[i + 2], s3 = csr[i + 3];
        ushort4 v0 = *(const ushort4*)(hb + (size_t)s0 * HIDDEN + lane * 4);
        ushort4 v1 = *(const ushort4*)(hb + (size_t)s1 * HIDDEN + lane * 4);
        ushort4 v2 = *(const ushort4*)(hb + (size_t)s2 * HIDDEN + lane * 4);
        ushort4 v3 = *(const ushort4*)(hb + (size_t)s3 * HIDDEN + lane * 4);
        a0[0] += bf2f(v0.x); a0[1] += bf2f(v0.y); a0[2] += bf2f(v0.z); a0[3] += bf2f(v0.w);
        a1[0] += bf2f(v1.x); a1[1] += bf2f(v1.y); a1[2] += bf2f(v1.z); a1[3] += bf2f(v1.w);
        a2[0] += bf2f(v2.x); a2[1] += bf2f(v2.y); a2[2] += bf2f(v2.z); a2[3] += bf2f(v2.w);
        a3[0] += bf2f(v3.x); a3[1] += bf2f(v3.y); a3[2] += bf2f(v3.z); a3[3] += bf2f(v3.w);
    }
    for (; i < en; ++i) {
        int s0 = csr[i];
        ushort4 v0 = *(const ushort4*)(hb + (size_t)s0 * HIDDEN + lane * 4);
        a0[0] += bf2f(v0.x); a0[1] += bf2f(v0.y); a0[2] += bf2f(v0.z); a0[3] += bf2f(v0.w);
    }
    float inv = 1.0f / fmaxf((float)dn, 1.0f);
    ushort4 r;
    r.x = f2bf(((a0[0] + a1[0]) + (a2[0] + a3[0])) * inv);
    r.y = f2bf(((a0[1] + a1[1]) + (a2[1] + a3[1])) * inv);
    r.z = f2bf(((a0[2] + a1[2]) + (a2[2] + a3[2])) * inv);
    r.w = f2bf(((a0[3] + a1[3]) + (a2[3] + a3[3])) * inv);
    *(ushort4*)(aggb + (size_t)node * HIDDEN + lane * 4) = r;
}

// ---------------- MFMA layer: hb = bf16(LN(ELU([aggb|hb] @ Wt^T + b_l))) ----------------
// 4 waves; wave w owns rows w*32..w*32+31 (2 frag-rows) x all 128 cols (8 frag-cols).
// A staged in LDS [128][AT_STRIDE] (80B stride: 16B-aligned, <=2-way bank alias = free).
// B-frags streamed from Wt[n][k] (64KB, L1/L2-resident).
// Frag maps: A row=lane&15, k=(lane>>4)*8+j; B col=lane&15, k=(lane>>4)*8+j;
// C/D col=lane&15, row=(lane>>4)*4+reg (verified m89).
__global__ __launch_bounds__(256) void layer_mfma(const unsigned short* __restrict__ aggb,
                                                  const unsigned short* __restrict__ Wt,
                                                  const float* __restrict__ b_l,
                                                  const float* __restrict__ gamma_,
                                                  const float* __restrict__ beta_,
                                                  unsigned short* __restrict__ hb) {
    __shared__ unsigned short At[LBM * AT_STRIDE];   // 10240B
    int t = threadIdx.x;
    int row0 = blockIdx.x * LBM;
    int w = t >> 6;          // wave 0..3
    int l = t & 63;
    int c = l & 15;          // frag col / A-row offset
    int g = l >> 4;          // 0..3
    f32x4 acc[2][8];
    #pragma unroll
    for (int fr = 0; fr < 2; ++fr)
        #pragma unroll
        for (int nf = 0; nf < 8; ++nf)
            acc[fr][nf] = (f32x4){0.f, 0.f, 0.f, 0.f};

    for (int kt = 0; kt < 8; ++kt) {
        const unsigned short* Asrc = (kt < 4) ? aggb : hb;
        int kb = (kt & 3) * 32;
        __syncthreads();   // protect At from previous iter's readers
        // stage A tile: 128 rows x 32 bf16 (64B) = 512 x 16B chunks
        #pragma unroll
        for (int i = 0; i < 2; ++i) {
            int ch = i * 256 + t;
            int row = ch >> 2, cc = ch & 3;
            int node = row0 + row;
            uint4 v = make_uint4(0u, 0u, 0u, 0u);
            if (node < N_NODES)
                v = *(const uint4*)(Asrc + (size_t)node * HIDDEN + kb + cc * 8);
            *(uint4*)&At[row * AT_STRIDE + cc * 8] = v;
        }
        __syncthreads();
        // A frags for this wave's two 16-row groups
        bf16x8 a0 = *(const bf16x8*)&At[(w * 32 + c) * AT_STRIDE + g * 8];
        bf16x8 a1 = *(const bf16x8*)&At[(w * 32 + 16 + c) * AT_STRIDE + g * 8];
        #pragma unroll
        for (int nf = 0; nf < 8; ++nf) {
            bf16x8 b = *(const bf16x8*)(Wt + (size_t)(nf * 16 + c) * 256 + kt * 32 + g * 8);
            acc[0][nf] = __builtin_amdgcn_mfma_f32_16x16x32_bf16(a0, b, acc[0][nf], 0, 0, 0);
            acc[1][nf] = __builtin_amdgcn_mfma_f32_16x16x32_bf16(a1, b, acc[1][nf], 0, 0, 0);
        }
    }
    // epilogue: +b_l, ELU, LayerNorm (rows live across the 16 lanes sharing g)
    float bl[8], ga[8], be[8];
    #pragma unroll
    for (int nf = 0; nf < 8; ++nf) {
        int col = nf * 16 + c;
        bl[nf] = b_l[col]; ga[nf] = gamma_[col]; be[nf] = beta_[col];
    }
    const float inv128 = 1.0f / 128.0f;
    #pragma unroll
    for (int fr = 0; fr < 2; ++fr) {
        #pragma unroll
        for (int r = 0; r < 4; ++r) {
            int node = row0 + w * 32 + fr * 16 + g * 4 + r;
            float v[8];
            float s = 0.f, sq = 0.f;
            #pragma unroll
            for (int nf = 0; nf < 8; ++nf) {
                float xv = acc[fr][nf][r] + bl[nf];
                xv = (xv > 0.f) ? xv : expm1f(xv);
                v[nf] = xv; s += xv; sq += xv * xv;
            }
            #pragma unroll
            for (int m = 8; m >= 1; m >>= 1) {
                s += __shfl_xor(s, m, 64);
                sq += __shfl_xor(sq, m, 64);
            }
            float mu = s * inv128;
            float var = sq * inv128 - mu * mu;
            float rstd = rsqrtf(var + LN_EPS);
            if (node < N_NODES) {
                #pragma unroll
                for (int nf = 0; nf < 8; ++nf)
                    hb[(size_t)node * HIDDEN + nf * 16 + c] =
                        f2bf((v[nf] - mu) * rstd * ga[nf] + be[nf]);
            }
        }
    }
}

// ---------------- fused pool + heads (bf16 h) ----------------
__global__ __launch_bounds__(256) void pool_head_kernel(const unsigned short* __restrict__ hb,
                                                        const int* __restrict__ batch,
                                                        const float* __restrict__ W_mem,
                                                        const float* __restrict__ b_mem,
                                                        const float* __restrict__ W_time,
                                                        const float* __restrict__ b_time,
                                                        float* __restrict__ out) {
    __shared__ float red[8][HIDDEN];
    int g = blockIdx.x;
    int t = threadIdx.x;
    int lane = t & 31;
    int grp = t >> 5;
    int lo = 0, hi = N_NODES;
    while (lo < hi) { int mid = (lo + hi) >> 1; if (batch[mid] < g) lo = mid + 1; else hi = mid; }
    int start = lo;
    hi = N_NODES;
    while (lo < hi) { int mid = (lo + hi) >> 1; if (batch[mid] < g + 1) lo = mid + 1; else hi = mid; }
    int end = lo;
    float a0 = 0.f, a1 = 0.f, a2 = 0.f, a3 = 0.f;
    for (int n = start + grp; n < end; n += 8) {
        ushort4 v = *(const ushort4*)(hb + (size_t)n * HIDDEN + lane * 4);
        a0 += bf2f(v.x); a1 += bf2f(v.y); a2 += bf2f(v.z); a3 += bf2f(v.w);
    }
    red[grp][lane * 4 + 0] = a0; red[grp][lane * 4 + 1] = a1;
    red[grp][lane * 4 + 2] = a2; red[grp][lane * 4 + 3] = a3;
    __syncthreads();
    if (t < HIDDEN) {
        float s = 0.f;
        #pragma unroll
        for (int i = 0; i < 8; ++i) s += red[i][t];
        float ic = 1.0f / fmaxf((float)(end - start), 1.0f);
        red[0][t] = s * ic;
    }
    __syncthreads();
    if (t < 64) {
        float p0 = red[0][t], p1 = red[0][t + 64];
        float dm = p0 * W_mem[t] + p1 * W_mem[t + 64];
        float dtv = p0 * W_time[t] + p1 * W_time[t + 64];
        #pragma unroll
        for (int m = 32; m >= 1; m >>= 1) {
            dm += __shfl_xor(dm, m, 64);
            dtv += __shfl_xor(dtv, m, 64);
        }
        if (t == 0) {
            out[g] = dm + b_mem[0];
            out[N_GRAPHS + g] = dtv + b_time[0];
        }
    }
}

extern "C" void kernel_launch(void* const* d_in, const int* in_sizes, int n_in,
                              void* d_out, int out_size, void* d_ws, size_t ws_size,
                              hipStream_t stream) {
    const float* x      = (const float*)d_in[0];
    const int*   edge   = (const int*)d_in[1];
    const int*   batch  = (const int*)d_in[2];
    const float* W_op   = (const float*)d_in[3];
    const float* b_op   = (const float*)d_in[4];
    const float* W_l    = (const float*)d_in[5];
    const float* b_l    = (const float*)d_in[6];
    const float* W_r    = (const float*)d_in[7];
    const float* gamma_ = (const float*)d_in[8];
    const float* beta_  = (const float*)d_in[9];
    const float* W_mem  = (const float*)d_in[10];
    const float* b_mem  = (const float*)d_in[11];
    const float* W_time = (const float*)d_in[12];
    const float* b_time = (const float*)d_in[13];
    const int* src = edge;
    const int* dst = edge + N_EDGES;

    char* ws = (char*)d_ws;
    const size_t hb_bytes = (size_t)N_NODES * HIDDEN * sizeof(unsigned short);  // 25.6MB
    unsigned short* hb    = (unsigned short*)ws;
    unsigned short* aggb  = (unsigned short*)(ws + hb_bytes);
    char*  p       = ws + 2 * hb_bytes;
    unsigned short* Wt = (unsigned short*)p;  p += (size_t)HIDDEN * 2 * HIDDEN * 2;  // 64KB
    int*   degi    = (int*)p;                 p += (size_t)N_NODES * 4;
    int*   offsets = (int*)p;                 p += (size_t)N_NODES * 4;
    int*   cursor  = (int*)p;                 p += (size_t)N_NODES * 4;
    int*   csr     = (int*)p;                 p += (size_t)N_EDGES * 4;
    int*   bsum    = (int*)p;                 p += 2048;
    int*   boff    = (int*)p;                 p += 2048;
    int*   histg   = (int*)p;                 p += 512;
    int*   bbase   = (int*)p;                 p += 512;
    int*   bcur    = (int*)p;                 p += 512;
    // stash (12.8MB) aliases aggb (25.6MB): aggb is dead until first gather,
    // which runs only after fill_pass has consumed the stash.
    uint2* stash   = (uint2*)aggb;

    hipMemsetAsync(degi, 0, (size_t)N_NODES * 4, stream);
    hipMemsetAsync(histg, 0, NBUCK * sizeof(int), stream);

    // per-node degree + offsets
    deg_int_kernel<<<(N_EDGES + 255) / 256, 256, 0, stream>>>(dst, degi);
    scan_block_sums<<<NBLK_SCAN, 256, 0, stream>>>(degi, bsum);
    scan_partials<<<1, 512, 0, stream>>>(bsum, boff);
    scan_final<<<NBLK_SCAN, 256, 0, stream>>>(degi, boff, offsets, cursor);

    // binned CSR build
    hist_bucket<<<NBIN, 256, 0, stream>>>(dst, histg);
    scan_bucket<<<1, 128, 0, stream>>>(histg, bbase, bcur);
    bin_pass<<<NBIN, 256, 0, stream>>>(src, dst, bcur, stash);
    fill_pass<<<NBUCK, 256, 0, stream>>>(stash, bbase, cursor, csr);

    // weights -> bf16 transposed; input projection -> bf16 h
    prep_w<<<128, 256, 0, stream>>>(W_l, W_r, Wt);
    proj_kernel<<<(N_NODES + 63) / 64, 256, 0, stream>>>(x, W_op, b_op, hb);

    // layers (cursor holds end offsets == offsets + deg)
    for (int layer = 0; layer < 2; ++layer) {
        gather_kernel<<<(int)(((size_t)N_NODES * 32 + 255) / 256), 256, 0, stream>>>(
            hb, csr, offsets, cursor, aggb);
        layer_mfma<<<(N_NODES + LBM - 1) / LBM, 256, 0, stream>>>(
            aggb, Wt, b_l, gamma_, beta_, hb);
    }

    // fused pooling + heads
    pool_head_kernel<<<N_GRAPHS, 256, 0, stream>>>(hb, batch, W_mem, b_mem, W_time, b_time, (float*)d_out);
}

// Round 12
// 495.383 us; speedup vs baseline: 12.4958x; 1.1063x over previous
//
#include <hip/hip_runtime.h>
#include <hip/hip_bf16.h>
#include <math.h>

#define N_NODES 100000
#define N_EDGES 1600000
#define N_FEAT 32
#define HIDDEN 128
#define N_GRAPHS 256
#define LN_EPS 1e-5f
#define NBLK_SCAN ((N_NODES + 255) / 256)   // 391

// CSR-build binning parameters
#define BSHIFT 10
#define BUCKN (1 << BSHIFT)                 // 1024 nodes per bucket
#define NBUCK 98                            // buckets of 1024 nodes
#define EPB 3840                            // edges per bin block
#define NBIN ((N_EDGES + EPB - 1) / EPB)    // 417

// MFMA layer tile
#define LBM 128                             // rows per block (4 waves x 32)
#define AT_STRIDE 40                        // LDS row stride in ushorts (80B: 16B-aligned, 2-way-max bank alias)

typedef __attribute__((ext_vector_type(8))) short bf16x8;   // 8 bf16 = 4 VGPRs
typedef __attribute__((ext_vector_type(4))) float f32x4;    // MFMA accumulator

__device__ __forceinline__ float bf2f(unsigned short u) {
    return __uint_as_float(((unsigned int)u) << 16);
}
__device__ __forceinline__ unsigned short f2bf(float f) {
    unsigned int u = __float_as_uint(f);
    u += 0x7FFFu + ((u >> 16) & 1u);        // round-to-nearest-even
    return (unsigned short)(u >> 16);
}

// ---------------- scan step 1 ----------------
__global__ __launch_bounds__(256) void scan_block_sums(const int* __restrict__ degi,
                                                       int* __restrict__ bsum) {
    __shared__ int red[256];
    int t = threadIdx.x;
    int i = blockIdx.x * 256 + t;
    red[t] = (i < N_NODES) ? degi[i] : 0;
    __syncthreads();
    #pragma unroll
    for (int off = 128; off > 0; off >>= 1) {
        if (t < off) red[t] += red[t + off];
        __syncthreads();
    }
    if (t == 0) bsum[blockIdx.x] = red[0];
}

// ---------------- scan step 2 ----------------
__global__ __launch_bounds__(512) void scan_partials(const int* __restrict__ bsum,
                                                     int* __restrict__ boff) {
    __shared__ int s[512];
    int t = threadIdx.x;
    int v = (t < NBLK_SCAN) ? bsum[t] : 0;
    s[t] = v;
    __syncthreads();
    for (int off = 1; off < 512; off <<= 1) {
        int x = s[t];
        if (t >= off) x += s[t - off];
        __syncthreads();
        s[t] = x;
        __syncthreads();
    }
    if (t < NBLK_SCAN) boff[t] = s[t] - v;
}

// ---------------- scan step 3 ----------------
__global__ __launch_bounds__(256) void scan_final(const int* __restrict__ degi,
                                                  const int* __restrict__ boff,
                                                  int* __restrict__ offsets,
                                                  int* __restrict__ cursor) {
    __shared__ int s[256];
    int t = threadIdx.x;
    int i = blockIdx.x * 256 + t;
    int v = (i < N_NODES) ? degi[i] : 0;
    s[t] = v;
    __syncthreads();
    for (int off = 1; off < 256; off <<= 1) {
        int x = s[t];
        if (t >= off) x += s[t - off];
        __syncthreads();
        s[t] = x;
        __syncthreads();
    }
    if (i < N_NODES) {
        int ex = s[t] - v + boff[blockIdx.x];
        offsets[i] = ex;
        cursor[i] = ex;
    }
}

// ---------------- bucket histogram ----------------
__global__ __launch_bounds__(256) void hist_bucket(const int* __restrict__ dst,
                                                   int* __restrict__ histg) {
    __shared__ int h[NBUCK];
    int t = threadIdx.x;
    if (t < NBUCK) h[t] = 0;
    __syncthreads();
    int base = blockIdx.x * EPB;
    #pragma unroll
    for (int i = 0; i < EPB / 256; ++i) {
        int e = base + i * 256 + t;
        if (e < N_EDGES) atomicAdd(&h[dst[e] >> BSHIFT], 1);
    }
    __syncthreads();
    if (t < NBUCK && h[t]) atomicAdd(&histg[t], h[t]);
}

// ---------------- bucket base scan ----------------
__global__ __launch_bounds__(128) void scan_bucket(const int* __restrict__ histg,
                                                   int* __restrict__ bbase,
                                                   int* __restrict__ bcur) {
    __shared__ int sb[128];
    int t = threadIdx.x;
    int v = (t < NBUCK) ? histg[t] : 0;
    sb[t] = v;
    __syncthreads();
    for (int off = 1; off < 128; off <<= 1) {
        int x = sb[t];
        if (t >= off) x += sb[t - off];
        __syncthreads();
        sb[t] = x;
        __syncthreads();
    }
    if (t < NBUCK) { bbase[t] = sb[t] - v; bcur[t] = sb[t] - v; }
    if (t == NBUCK - 1) bbase[NBUCK] = sb[t];
}

// ---------------- bin pass (locality-creating LDS counting sort) ----------------
__global__ __launch_bounds__(256) void bin_pass(const int* __restrict__ src,
                                                const int* __restrict__ dst,
                                                int* __restrict__ bcur,
                                                uint2* __restrict__ stash) {
    __shared__ int srcL[EPB];
    __shared__ int dstL[EPB];
    __shared__ int hist[NBUCK], lex[NBUCK], lcur[NBUCK], gbase[NBUCK];
    __shared__ int sb[128];
    int t = threadIdx.x;
    if (t < NBUCK) hist[t] = 0;
    __syncthreads();
    int base = blockIdx.x * EPB;
    #pragma unroll
    for (int i = 0; i < EPB / 256; ++i) {
        int e = base + i * 256 + t;
        if (e < N_EDGES) atomicAdd(&hist[dst[e] >> BSHIFT], 1);
    }
    __syncthreads();
    {
        int v = (t < NBUCK) ? hist[t] : 0;
        if (t < 128) sb[t] = v;
        __syncthreads();
        for (int off = 1; off < 128; off <<= 1) {
            int x = 0;
            if (t < 128) { x = sb[t]; if (t >= off) x += sb[t - off]; }
            __syncthreads();
            if (t < 128) sb[t] = x;
            __syncthreads();
        }
        if (t < NBUCK) {
            int ex = sb[t] - hist[t];
            lex[t] = ex; lcur[t] = ex;
            gbase[t] = atomicAdd(&bcur[t], hist[t]);
        }
    }
    __syncthreads();
    #pragma unroll
    for (int i = 0; i < EPB / 256; ++i) {
        int e = base + i * 256 + t;
        if (e < N_EDGES) {
            int d = dst[e];
            int p = atomicAdd(&lcur[d >> BSHIFT], 1);
            dstL[p] = d; srcL[p] = src[e];
        }
    }
    __syncthreads();
    int n_e = min(EPB, N_EDGES - base);
    #pragma unroll
    for (int i = 0; i < EPB / 256; ++i) {
        int idx = i * 256 + t;
        if (idx < n_e) {
            int lo = 0, hi = NBUCK - 1;
            while (lo < hi) { int mid = (lo + hi + 1) >> 1; if (lex[mid] <= idx) lo = mid; else hi = mid - 1; }
            int g = gbase[lo] + (idx - lex[lo]);
            stash[g] = make_uint2((unsigned)dstL[idx], (unsigned)srcL[idx]);
        }
    }
}

// ---------------- per-bucket degree from stash (replaces global-atomic deg pass) ----------------
// deg_int's 1.6M scattered global atomics cost 66us / 49.9MB HBM write (cross-XCD
// line bouncing on a 400KB buffer). The stash is already bucket-grouped, so count
// in LDS (no global traffic) and write degi coalesced. Also covers every node
// (zero-degree included) so the degi memset is gone too.
__global__ __launch_bounds__(256) void deg_local(const uint2* __restrict__ stash,
                                                 const int* __restrict__ bbase,
                                                 int* __restrict__ degi) {
    __shared__ int cnt[BUCKN];   // 4KB
    int k = blockIdx.x;
    int t = threadIdx.x;
    #pragma unroll
    for (int i = 0; i < BUCKN / 256; ++i) cnt[i * 256 + t] = 0;
    __syncthreads();
    int beg = bbase[k], end = bbase[k + 1];
    for (int i = beg + t; i < end; i += 256)
        atomicAdd(&cnt[stash[i].x & (BUCKN - 1)], 1);
    __syncthreads();
    int nb = k << BSHIFT;
    #pragma unroll
    for (int i = 0; i < BUCKN / 256; ++i) {
        int node = nb + i * 256 + t;
        if (node < N_NODES) degi[node] = cnt[i * 256 + t];
    }
}

// ---------------- fill pass ----------------
__global__ __launch_bounds__(256) void fill_pass(const uint2* __restrict__ stash,
                                                 const int* __restrict__ bbase,
                                                 int* __restrict__ cursor,
                                                 int* __restrict__ csr) {
    int k = blockIdx.x;
    int beg = bbase[k], end = bbase[k + 1];
    for (int i = beg + threadIdx.x; i < end; i += 256) {
        uint2 p = stash[i];
        int pos = atomicAdd(&cursor[p.x], 1);
        csr[pos] = (int)p.y;
    }
}

// ---------------- weight prep: Wt[n][k] = bf16 of [W_l; W_r][k][n] ----------------
__global__ __launch_bounds__(256) void prep_w(const float* __restrict__ Wl,
                                              const float* __restrict__ Wr,
                                              unsigned short* __restrict__ Wt) {
    int idx = blockIdx.x * 256 + threadIdx.x;
    if (idx < HIDDEN * 2 * HIDDEN) {
        int n = idx >> 8, k = idx & 255;
        float v = (k < HIDDEN) ? Wl[k * HIDDEN + n] : Wr[(k - HIDDEN) * HIDDEN + n];
        Wt[n * 256 + k] = f2bf(v);
    }
}

// ---------------- input projection -> bf16 h ----------------
__global__ __launch_bounds__(256) void proj_kernel(const float* __restrict__ x,
                                                   const float* __restrict__ W,
                                                   const float* __restrict__ b,
                                                   unsigned short* __restrict__ hb) {
    __shared__ float ws[N_FEAT][HIDDEN];
    __shared__ float bs[HIDDEN];
    __shared__ float xs[64][N_FEAT];
    int t = threadIdx.x;
    #pragma unroll
    for (int i = 0; i < 4; ++i)
        ((float4*)&ws[0][0])[t + i * 256] = ((const float4*)W)[t + i * 256];
    if (t < 32) ((float4*)bs)[t] = ((const float4*)b)[t];
    int base = blockIdx.x * 64;
    #pragma unroll
    for (int i = 0; i < 2; ++i) {
        int f4 = t + i * 256;
        int node = base + (f4 >> 3);
        float4 v = make_float4(0.f, 0.f, 0.f, 0.f);
        if (node < N_NODES) v = ((const float4*)x)[(size_t)node * 8 + (f4 & 7)];
        ((float4*)&xs[0][0])[f4] = v;
    }
    __syncthreads();
    int c0 = (t & 31) * 4;
    int nslot = t >> 5;
    for (int it = 0; it < 8; ++it) {
        int nl = nslot + it * 8;
        int node = base + nl;
        float acc0 = bs[c0], acc1 = bs[c0 + 1], acc2 = bs[c0 + 2], acc3 = bs[c0 + 3];
        #pragma unroll
        for (int k = 0; k < N_FEAT; ++k) {
            float a = xs[nl][k];
            float4 w = *(const float4*)&ws[k][c0];
            acc0 += a * w.x; acc1 += a * w.y; acc2 += a * w.z; acc3 += a * w.w;
        }
        if (node < N_NODES) {
            ushort4 o;
            o.x = f2bf(acc0); o.y = f2bf(acc1); o.z = f2bf(acc2); o.w = f2bf(acc3);
            *(ushort4*)&hb[(size_t)node * HIDDEN + c0] = o;
        }
    }
}

// ---------------- gather (bf16 payload): agg_b[n] = mean of hb[src] ----------------
__global__ __launch_bounds__(256) void gather_kernel(const unsigned short* __restrict__ hb,
                                                     const int* __restrict__ csr,
                                                     const int* __restrict__ offsets,
                                                     const int* __restrict__ cursor_end,
                                                     unsigned short* __restrict__ aggb) {
    int node = (int)(((size_t)blockIdx.x * blockDim.x + threadIdx.x) >> 5);
    int lane = threadIdx.x & 31;
    if (node >= N_NODES) return;
    int st = offsets[node];
    int en = cursor_end[node];
    int dn = en - st;
    float a0[4] = {0.f, 0.f, 0.f, 0.f};
    float a1[4] = {0.f, 0.f, 0.f, 0.f};
    float a2[4] = {0.f, 0.f, 0.f, 0.f};
    float a3[4] = {0.f, 0.f, 0.f, 0.f};
    int i = st;
    for (; i + 4 <= en; i += 4) {
        int s0 = csr[i], s1 = csr[i + 1], s2 = csr[i + 2], s3 = csr[i + 3];
        ushort4 v0 = *(const ushort4*)(hb + (size_t)s0 * HIDDEN + lane * 4);
        ushort4 v1 = *(const ushort4*)(hb + (size_t)s1 * HIDDEN + lane * 4);
        ushort4 v2 = *(const ushort4*)(hb + (size_t)s2 * HIDDEN + lane * 4);
        ushort4 v3 = *(const ushort4*)(hb + (size_t)s3 * HIDDEN + lane * 4);
        a0[0] += bf2f(v0.x); a0[1] += bf2f(v0.y); a0[2] += bf2f(v0.z); a0[3] += bf2f(v0.w);
        a1[0] += bf2f(v1.x); a1[1] += bf2f(v1.y); a1[2] += bf2f(v1.z); a1[3] += bf2f(v1.w);
        a2[0] += bf2f(v2.x); a2[1] += bf2f(v2.y); a2[2] += bf2f(v2.z); a2[3] += bf2f(v2.w);
        a3[0] += bf2f(v3.x); a3[1] += bf2f(v3.y); a3[2] += bf2f(v3.z); a3[3] += bf2f(v3.w);
    }
    for (; i < en; ++i) {
        int s0 = csr[i];
        ushort4 v0 = *(const ushort4*)(hb + (size_t)s0 * HIDDEN + lane * 4);
        a0[0] += bf2f(v0.x); a0[1] += bf2f(v0.y); a0[2] += bf2f(v0.z); a0[3] += bf2f(v0.w);
    }
    float inv = 1.0f / fmaxf((float)dn, 1.0f);
    ushort4 r;
    r.x = f2bf(((a0[0] + a1[0]) + (a2[0] + a3[0])) * inv);
    r.y = f2bf(((a0[1] + a1[1]) + (a2[1] + a3[1])) * inv);
    r.z = f2bf(((a0[2] + a1[2]) + (a2[2] + a3[2])) * inv);
    r.w = f2bf(((a0[3] + a1[3]) + (a2[3] + a3[3])) * inv);
    *(ushort4*)(aggb + (size_t)node * HIDDEN + lane * 4) = r;
}

// ---------------- MFMA layer: hb = bf16(LN(ELU([aggb|hb] @ Wt^T + b_l))) ----------------
__global__ __launch_bounds__(256) void layer_mfma(const unsigned short* __restrict__ aggb,
                                                  const unsigned short* __restrict__ Wt,
                                                  const float* __restrict__ b_l,
                                                  const float* __restrict__ gamma_,
                                                  const float* __restrict__ beta_,
                                                  unsigned short* __restrict__ hb) {
    __shared__ unsigned short At[LBM * AT_STRIDE];   // 10240B
    int t = threadIdx.x;
    int row0 = blockIdx.x * LBM;
    int w = t >> 6;          // wave 0..3
    int l = t & 63;
    int c = l & 15;          // frag col / A-row offset
    int g = l >> 4;          // 0..3
    f32x4 acc[2][8];
    #pragma unroll
    for (int fr = 0; fr < 2; ++fr)
        #pragma unroll
        for (int nf = 0; nf < 8; ++nf)
            acc[fr][nf] = (f32x4){0.f, 0.f, 0.f, 0.f};

    for (int kt = 0; kt < 8; ++kt) {
        const unsigned short* Asrc = (kt < 4) ? aggb : hb;
        int kb = (kt & 3) * 32;
        __syncthreads();   // protect At from previous iter's readers
        // stage A tile: 128 rows x 32 bf16 (64B) = 512 x 16B chunks
        #pragma unroll
        for (int i = 0; i < 2; ++i) {
            int ch = i * 256 + t;
            int row = ch >> 2, cc = ch & 3;
            int node = row0 + row;
            uint4 v = make_uint4(0u, 0u, 0u, 0u);
            if (node < N_NODES)
                v = *(const uint4*)(Asrc + (size_t)node * HIDDEN + kb + cc * 8);
            *(uint4*)&At[row * AT_STRIDE + cc * 8] = v;
        }
        __syncthreads();
        // A frags for this wave's two 16-row groups
        bf16x8 a0 = *(const bf16x8*)&At[(w * 32 + c) * AT_STRIDE + g * 8];
        bf16x8 a1 = *(const bf16x8*)&At[(w * 32 + 16 + c) * AT_STRIDE + g * 8];
        #pragma unroll
        for (int nf = 0; nf < 8; ++nf) {
            bf16x8 b = *(const bf16x8*)(Wt + (size_t)(nf * 16 + c) * 256 + kt * 32 + g * 8);
            acc[0][nf] = __builtin_amdgcn_mfma_f32_16x16x32_bf16(a0, b, acc[0][nf], 0, 0, 0);
            acc[1][nf] = __builtin_amdgcn_mfma_f32_16x16x32_bf16(a1, b, acc[1][nf], 0, 0, 0);
        }
    }
    // epilogue: +b_l, ELU, LayerNorm (rows live across the 16 lanes sharing g)
    float bl[8], ga[8], be[8];
    #pragma unroll
    for (int nf = 0; nf < 8; ++nf) {
        int col = nf * 16 + c;
        bl[nf] = b_l[col]; ga[nf] = gamma_[col]; be[nf] = beta_[col];
    }
    const float inv128 = 1.0f / 128.0f;
    #pragma unroll
    for (int fr = 0; fr < 2; ++fr) {
        #pragma unroll
        for (int r = 0; r < 4; ++r) {
            int node = row0 + w * 32 + fr * 16 + g * 4 + r;
            float v[8];
            float s = 0.f, sq = 0.f;
            #pragma unroll
            for (int nf = 0; nf < 8; ++nf) {
                float xv = acc[fr][nf][r] + bl[nf];
                xv = (xv > 0.f) ? xv : expm1f(xv);
                v[nf] = xv; s += xv; sq += xv * xv;
            }
            #pragma unroll
            for (int m = 8; m >= 1; m >>= 1) {
                s += __shfl_xor(s, m, 64);
                sq += __shfl_xor(sq, m, 64);
            }
            float mu = s * inv128;
            float var = sq * inv128 - mu * mu;
            float rstd = rsqrtf(var + LN_EPS);
            if (node < N_NODES) {
                #pragma unroll
                for (int nf = 0; nf < 8; ++nf)
                    hb[(size_t)node * HIDDEN + nf * 16 + c] =
                        f2bf((v[nf] - mu) * rstd * ga[nf] + be[nf]);
            }
        }
    }
}

// ---------------- fused pool + heads (bf16 h) ----------------
__global__ __launch_bounds__(256) void pool_head_kernel(const unsigned short* __restrict__ hb,
                                                        const int* __restrict__ batch,
                                                        const float* __restrict__ W_mem,
                                                        const float* __restrict__ b_mem,
                                                        const float* __restrict__ W_time,
                                                        const float* __restrict__ b_time,
                                                        float* __restrict__ out) {
    __shared__ float red[8][HIDDEN];
    int g = blockIdx.x;
    int t = threadIdx.x;
    int lane = t & 31;
    int grp = t >> 5;
    int lo = 0, hi = N_NODES;
    while (lo < hi) { int mid = (lo + hi) >> 1; if (batch[mid] < g) lo = mid + 1; else hi = mid; }
    int start = lo;
    hi = N_NODES;
    while (lo < hi) { int mid = (lo + hi) >> 1; if (batch[mid] < g + 1) lo = mid + 1; else hi = mid; }
    int end = lo;
    float a0 = 0.f, a1 = 0.f, a2 = 0.f, a3 = 0.f;
    for (int n = start + grp; n < end; n += 8) {
        ushort4 v = *(const ushort4*)(hb + (size_t)n * HIDDEN + lane * 4);
        a0 += bf2f(v.x); a1 += bf2f(v.y); a2 += bf2f(v.z); a3 += bf2f(v.w);
    }
    red[grp][lane * 4 + 0] = a0; red[grp][lane * 4 + 1] = a1;
    red[grp][lane * 4 + 2] = a2; red[grp][lane * 4 + 3] = a3;
    __syncthreads();
    if (t < HIDDEN) {
        float s = 0.f;
        #pragma unroll
        for (int i = 0; i < 8; ++i) s += red[i][t];
        float ic = 1.0f / fmaxf((float)(end - start), 1.0f);
        red[0][t] = s * ic;
    }
    __syncthreads();
    if (t < 64) {
        float p0 = red[0][t], p1 = red[0][t + 64];
        float dm = p0 * W_mem[t] + p1 * W_mem[t + 64];
        float dtv = p0 * W_time[t] + p1 * W_time[t + 64];
        #pragma unroll
        for (int m = 32; m >= 1; m >>= 1) {
            dm += __shfl_xor(dm, m, 64);
            dtv += __shfl_xor(dtv, m, 64);
        }
        if (t == 0) {
            out[g] = dm + b_mem[0];
            out[N_GRAPHS + g] = dtv + b_time[0];
        }
    }
}

extern "C" void kernel_launch(void* const* d_in, const int* in_sizes, int n_in,
                              void* d_out, int out_size, void* d_ws, size_t ws_size,
                              hipStream_t stream) {
    const float* x      = (const float*)d_in[0];
    const int*   edge   = (const int*)d_in[1];
    const int*   batch  = (const int*)d_in[2];
    const float* W_op   = (const float*)d_in[3];
    const float* b_op   = (const float*)d_in[4];
    const float* W_l    = (const float*)d_in[5];
    const float* b_l    = (const float*)d_in[6];
    const float* W_r    = (const float*)d_in[7];
    const float* gamma_ = (const float*)d_in[8];
    const float* beta_  = (const float*)d_in[9];
    const float* W_mem  = (const float*)d_in[10];
    const float* b_mem  = (const float*)d_in[11];
    const float* W_time = (const float*)d_in[12];
    const float* b_time = (const float*)d_in[13];
    const int* src = edge;
    const int* dst = edge + N_EDGES;

    char* ws = (char*)d_ws;
    const size_t hb_bytes = (size_t)N_NODES * HIDDEN * sizeof(unsigned short);  // 25.6MB
    unsigned short* hb    = (unsigned short*)ws;
    unsigned short* aggb  = (unsigned short*)(ws + hb_bytes);
    char*  p       = ws + 2 * hb_bytes;
    unsigned short* Wt = (unsigned short*)p;  p += (size_t)HIDDEN * 2 * HIDDEN * 2;  // 64KB
    int*   degi    = (int*)p;                 p += (size_t)N_NODES * 4;
    int*   offsets = (int*)p;                 p += (size_t)N_NODES * 4;
    int*   cursor  = (int*)p;                 p += (size_t)N_NODES * 4;
    int*   csr     = (int*)p;                 p += (size_t)N_EDGES * 4;
    int*   bsum    = (int*)p;                 p += 2048;
    int*   boff    = (int*)p;                 p += 2048;
    int*   histg   = (int*)p;                 p += 512;
    int*   bbase   = (int*)p;                 p += 512;
    int*   bcur    = (int*)p;                 p += 512;
    // stash (12.8MB) aliases aggb (25.6MB): aggb is dead until first gather,
    // which runs only after fill_pass/deg_local have consumed the stash.
    uint2* stash   = (uint2*)aggb;

    hipMemsetAsync(histg, 0, NBUCK * sizeof(int), stream);

    // binned CSR build: hist -> bases -> LDS-sort to stash
    hist_bucket<<<NBIN, 256, 0, stream>>>(dst, histg);
    scan_bucket<<<1, 128, 0, stream>>>(histg, bbase, bcur);
    bin_pass<<<NBIN, 256, 0, stream>>>(src, dst, bcur, stash);

    // degrees from stash (LDS counting, coalesced write; covers all nodes)
    deg_local<<<NBUCK, 256, 0, stream>>>(stash, bbase, degi);

    // per-node offsets
    scan_block_sums<<<NBLK_SCAN, 256, 0, stream>>>(degi, bsum);
    scan_partials<<<1, 512, 0, stream>>>(bsum, boff);
    scan_final<<<NBLK_SCAN, 256, 0, stream>>>(degi, boff, offsets, cursor);

    // scatter stash into final per-node CSR slots
    fill_pass<<<NBUCK, 256, 0, stream>>>(stash, bbase, cursor, csr);

    // weights -> bf16 transposed; input projection -> bf16 h
    prep_w<<<128, 256, 0, stream>>>(W_l, W_r, Wt);
    proj_kernel<<<(N_NODES + 63) / 64, 256, 0, stream>>>(x, W_op, b_op, hb);

    // layers (cursor holds end offsets == offsets + deg)
    for (int layer = 0; layer < 2; ++layer) {
        gather_kernel<<<(int)(((size_t)N_NODES * 32 + 255) / 256), 256, 0, stream>>>(
            hb, csr, offsets, cursor, aggb);
        layer_mfma<<<(N_NODES + LBM - 1) / LBM, 256, 0, stream>>>(
            aggb, Wt, b_l, gamma_, beta_, hb);
    }

    // fused pooling + heads
    pool_head_kernel<<<N_GRAPHS, 256, 0, stream>>>(hb, batch, W_mem, b_mem, W_time, b_time, (float*)d_out);
}

// Round 13
// 454.152 us; speedup vs baseline: 13.6303x; 1.0908x over previous
//
#include <hip/hip_runtime.h>
#include <hip/hip_bf16.h>
#include <math.h>

#define N_NODES 100000
#define N_EDGES 1600000
#define N_FEAT 32
#define HIDDEN 128
#define N_GRAPHS 256
#define LN_EPS 1e-5f

// CSR-build binning parameters
#define BSHIFT 10
#define BUCKN (1 << BSHIFT)                 // 1024 nodes per bucket
#define NBUCK 98                            // buckets of 1024 nodes
#define EPB 3840                            // edges per bin block
#define NBIN ((N_EDGES + EPB - 1) / EPB)    // 417
#define CAP 24576                           // LDS staging capacity (expected max bucket ~16.9K)

// MFMA layer tile
#define LBM 128                             // rows per block (4 waves x 32)
#define AT_STRIDE 40                        // LDS row stride in ushorts

typedef __attribute__((ext_vector_type(8))) short bf16x8;
typedef __attribute__((ext_vector_type(4))) float f32x4;

__device__ __forceinline__ float bf2f(unsigned short u) {
    return __uint_as_float(((unsigned int)u) << 16);
}
__device__ __forceinline__ unsigned short f2bf(float f) {
    unsigned int u = __float_as_uint(f);
    u += 0x7FFFu + ((u >> 16) & 1u);        // round-to-nearest-even
    return (unsigned short)(u >> 16);
}

// ---------------- bucket histogram ----------------
__global__ __launch_bounds__(256) void hist_bucket(const int* __restrict__ dst,
                                                   int* __restrict__ histg) {
    __shared__ int h[NBUCK];
    int t = threadIdx.x;
    if (t < NBUCK) h[t] = 0;
    __syncthreads();
    int base = blockIdx.x * EPB;
    #pragma unroll
    for (int i = 0; i < EPB / 256; ++i) {
        int e = base + i * 256 + t;
        if (e < N_EDGES) atomicAdd(&h[dst[e] >> BSHIFT], 1);
    }
    __syncthreads();
    if (t < NBUCK && h[t]) atomicAdd(&histg[t], h[t]);
}

// ---------------- bucket base scan ----------------
__global__ __launch_bounds__(128) void scan_bucket(const int* __restrict__ histg,
                                                   int* __restrict__ bbase,
                                                   int* __restrict__ bcur) {
    __shared__ int sb[128];
    int t = threadIdx.x;
    int v = (t < NBUCK) ? histg[t] : 0;
    sb[t] = v;
    __syncthreads();
    for (int off = 1; off < 128; off <<= 1) {
        int x = sb[t];
        if (t >= off) x += sb[t - off];
        __syncthreads();
        sb[t] = x;
        __syncthreads();
    }
    if (t < NBUCK) { bbase[t] = sb[t] - v; bcur[t] = sb[t] - v; }
    if (t == NBUCK - 1) bbase[NBUCK] = sb[t];
}

// ---------------- bin pass (locality-creating LDS counting sort) ----------------
__global__ __launch_bounds__(256) void bin_pass(const int* __restrict__ src,
                                                const int* __restrict__ dst,
                                                int* __restrict__ bcur,
                                                uint2* __restrict__ stash) {
    __shared__ int srcL[EPB];
    __shared__ int dstL[EPB];
    __shared__ int hist[NBUCK], lex[NBUCK], lcur[NBUCK], gbase[NBUCK];
    __shared__ int sb[128];
    int t = threadIdx.x;
    if (t < NBUCK) hist[t] = 0;
    __syncthreads();
    int base = blockIdx.x * EPB;
    #pragma unroll
    for (int i = 0; i < EPB / 256; ++i) {
        int e = base + i * 256 + t;
        if (e < N_EDGES) atomicAdd(&hist[dst[e] >> BSHIFT], 1);
    }
    __syncthreads();
    {
        int v = (t < NBUCK) ? hist[t] : 0;
        if (t < 128) sb[t] = v;
        __syncthreads();
        for (int off = 1; off < 128; off <<= 1) {
            int x = 0;
            if (t < 128) { x = sb[t]; if (t >= off) x += sb[t - off]; }
            __syncthreads();
            if (t < 128) sb[t] = x;
            __syncthreads();
        }
        if (t < NBUCK) {
            int ex = sb[t] - hist[t];
            lex[t] = ex; lcur[t] = ex;
            gbase[t] = atomicAdd(&bcur[t], hist[t]);
        }
    }
    __syncthreads();
    #pragma unroll
    for (int i = 0; i < EPB / 256; ++i) {
        int e = base + i * 256 + t;
        if (e < N_EDGES) {
            int d = dst[e];
            int p = atomicAdd(&lcur[d >> BSHIFT], 1);
            dstL[p] = d; srcL[p] = src[e];
        }
    }
    __syncthreads();
    int n_e = min(EPB, N_EDGES - base);
    #pragma unroll
    for (int i = 0; i < EPB / 256; ++i) {
        int idx = i * 256 + t;
        if (idx < n_e) {
            int lo = 0, hi = NBUCK - 1;
            while (lo < hi) { int mid = (lo + hi + 1) >> 1; if (lex[mid] <= idx) lo = mid; else hi = mid - 1; }
            int g = gbase[lo] + (idx - lex[lo]);
            stash[g] = make_uint2((unsigned)dstL[idx], (unsigned)srcL[idx]);
        }
    }
}

// ---------------- fused CSR finalize: one block per bucket, all-LDS ----------------
// Bucket k's edges occupy stash[bbase[k]..bbase[k+1]) AND its csr region is the
// same range (csr is node-ordered, bucket nodes contiguous). So: LDS count ->
// LDS scan -> LDS-atomic slot assign -> scatter src into LDS -> coalesced copy
// to csr. Zero global atomics (fill_pass's 1.6M cursor atomics cost 61us /
// 60.8MB HBM write - atomics write back ~32B each). offsets/ends written
// coalesced; lcur after scatter == local end, so ends come free. Replaces
// deg_local + 3 scan kernels + fill_pass.
__global__ __launch_bounds__(256) void csr_bucket(const uint2* __restrict__ stash,
                                                  const int* __restrict__ bbase,
                                                  int* __restrict__ offsets,
                                                  int* __restrict__ ends,
                                                  int* __restrict__ csr) {
    __shared__ int cnt[BUCKN];     // counts -> then lcur (cursor) -> final = local end
    __shared__ int ex[BUCKN];      // exclusive scan (local offsets)
    __shared__ int sb[256];
    __shared__ int srcL[CAP];      // 96KB staging
    int k = blockIdx.x;
    int t = threadIdx.x;
    int beg = bbase[k], end = bbase[k + 1];
    int ne = end - beg;
    #pragma unroll
    for (int i = 0; i < BUCKN / 256; ++i) cnt[i * 256 + t] = 0;
    __syncthreads();
    for (int i = beg + t; i < end; i += 256)
        atomicAdd(&cnt[stash[i].x & (BUCKN - 1)], 1);
    __syncthreads();
    // two-level exclusive scan over 1024: thread t owns cnt[4t..4t+3]
    int c0 = cnt[t * 4], c1 = cnt[t * 4 + 1], c2 = cnt[t * 4 + 2], c3 = cnt[t * 4 + 3];
    int gs = c0 + c1 + c2 + c3;
    sb[t] = gs;
    __syncthreads();
    for (int off = 1; off < 256; off <<= 1) {
        int x = sb[t];
        if (t >= off) x += sb[t - off];
        __syncthreads();
        sb[t] = x;
        __syncthreads();
    }
    int gbase_ = sb[t] - gs;   // exclusive base for this thread's group of 4
    ex[t * 4]     = gbase_;
    ex[t * 4 + 1] = gbase_ + c0;
    ex[t * 4 + 2] = gbase_ + c0 + c1;
    ex[t * 4 + 3] = gbase_ + c0 + c1 + c2;
    __syncthreads();
    // reset cursors to ex
    #pragma unroll
    for (int i = 0; i < BUCKN / 256; ++i) cnt[i * 256 + t] = ex[i * 256 + t];
    __syncthreads();
    // LDS-atomic slot assignment + LDS scatter
    for (int i = beg + t; i < end; i += 256) {
        uint2 p = stash[i];
        int pos = atomicAdd(&cnt[p.x & (BUCKN - 1)], 1);
        if (pos < CAP) srcL[pos] = (int)p.y;
        else csr[beg + pos] = (int)p.y;   // overflow fallback (statistically unreachable)
    }
    __syncthreads();
    // coalesced copy-out
    int lim = min(ne, CAP);
    for (int i = t; i < lim; i += 256) csr[beg + i] = srcL[i];
    // offsets/ends coalesced (cnt now holds local end positions)
    int nb = k << BSHIFT;
    #pragma unroll
    for (int i = 0; i < BUCKN / 256; ++i) {
        int idx = i * 256 + t;
        int node = nb + idx;
        if (node < N_NODES) {
            offsets[node] = beg + ex[idx];
            ends[node] = beg + cnt[idx];
        }
    }
}

// ---------------- weight prep: Wt[n][k] = bf16 of [W_l; W_r][k][n] ----------------
__global__ __launch_bounds__(256) void prep_w(const float* __restrict__ Wl,
                                              const float* __restrict__ Wr,
                                              unsigned short* __restrict__ Wt) {
    int idx = blockIdx.x * 256 + threadIdx.x;
    if (idx < HIDDEN * 2 * HIDDEN) {
        int n = idx >> 8, k = idx & 255;
        float v = (k < HIDDEN) ? Wl[k * HIDDEN + n] : Wr[(k - HIDDEN) * HIDDEN + n];
        Wt[n * 256 + k] = f2bf(v);
    }
}

// ---------------- input projection -> bf16 h ----------------
__global__ __launch_bounds__(256) void proj_kernel(const float* __restrict__ x,
                                                   const float* __restrict__ W,
                                                   const float* __restrict__ b,
                                                   unsigned short* __restrict__ hb) {
    __shared__ float ws[N_FEAT][HIDDEN];
    __shared__ float bs[HIDDEN];
    __shared__ float xs[64][N_FEAT];
    int t = threadIdx.x;
    #pragma unroll
    for (int i = 0; i < 4; ++i)
        ((float4*)&ws[0][0])[t + i * 256] = ((const float4*)W)[t + i * 256];
    if (t < 32) ((float4*)bs)[t] = ((const float4*)b)[t];
    int base = blockIdx.x * 64;
    #pragma unroll
    for (int i = 0; i < 2; ++i) {
        int f4 = t + i * 256;
        int node = base + (f4 >> 3);
        float4 v = make_float4(0.f, 0.f, 0.f, 0.f);
        if (node < N_NODES) v = ((const float4*)x)[(size_t)node * 8 + (f4 & 7)];
        ((float4*)&xs[0][0])[f4] = v;
    }
    __syncthreads();
    int c0 = (t & 31) * 4;
    int nslot = t >> 5;
    for (int it = 0; it < 8; ++it) {
        int nl = nslot + it * 8;
        int node = base + nl;
        float acc0 = bs[c0], acc1 = bs[c0 + 1], acc2 = bs[c0 + 2], acc3 = bs[c0 + 3];
        #pragma unroll
        for (int k = 0; k < N_FEAT; ++k) {
            float a = xs[nl][k];
            float4 w = *(const float4*)&ws[k][c0];
            acc0 += a * w.x; acc1 += a * w.y; acc2 += a * w.z; acc3 += a * w.w;
        }
        if (node < N_NODES) {
            ushort4 o;
            o.x = f2bf(acc0); o.y = f2bf(acc1); o.z = f2bf(acc2); o.w = f2bf(acc3);
            *(ushort4*)&hb[(size_t)node * HIDDEN + c0] = o;
        }
    }
}

// ---------------- gather (bf16 payload): agg_b[n] = mean of hb[src] ----------------
__global__ __launch_bounds__(256) void gather_kernel(const unsigned short* __restrict__ hb,
                                                     const int* __restrict__ csr,
                                                     const int* __restrict__ offsets,
                                                     const int* __restrict__ ends,
                                                     unsigned short* __restrict__ aggb) {
    int node = (int)(((size_t)blockIdx.x * blockDim.x + threadIdx.x) >> 5);
    int lane = threadIdx.x & 31;
    if (node >= N_NODES) return;
    int st = offsets[node];
    int en = ends[node];
    int dn = en - st;
    float a0[4] = {0.f, 0.f, 0.f, 0.f};
    float a1[4] = {0.f, 0.f, 0.f, 0.f};
    float a2[4] = {0.f, 0.f, 0.f, 0.f};
    float a3[4] = {0.f, 0.f, 0.f, 0.f};
    int i = st;
    for (; i + 4 <= en; i += 4) {
        int s0 = csr[i], s1 = csr[i + 1], s2 = csr[i + 2], s3 = csr[i + 3];
        ushort4 v0 = *(const ushort4*)(hb + (size_t)s0 * HIDDEN + lane * 4);
        ushort4 v1 = *(const ushort4*)(hb + (size_t)s1 * HIDDEN + lane * 4);
        ushort4 v2 = *(const ushort4*)(hb + (size_t)s2 * HIDDEN + lane * 4);
        ushort4 v3 = *(const ushort4*)(hb + (size_t)s3 * HIDDEN + lane * 4);
        a0[0] += bf2f(v0.x); a0[1] += bf2f(v0.y); a0[2] += bf2f(v0.z); a0[3] += bf2f(v0.w);
        a1[0] += bf2f(v1.x); a1[1] += bf2f(v1.y); a1[2] += bf2f(v1.z); a1[3] += bf2f(v1.w);
        a2[0] += bf2f(v2.x); a2[1] += bf2f(v2.y); a2[2] += bf2f(v2.z); a2[3] += bf2f(v2.w);
        a3[0] += bf2f(v3.x); a3[1] += bf2f(v3.y); a3[2] += bf2f(v3.z); a3[3] += bf2f(v3.w);
    }
    for (; i < en; ++i) {
        int s0 = csr[i];
        ushort4 v0 = *(const ushort4*)(hb + (size_t)s0 * HIDDEN + lane * 4);
        a0[0] += bf2f(v0.x); a0[1] += bf2f(v0.y); a0[2] += bf2f(v0.z); a0[3] += bf2f(v0.w);
    }
    float inv = 1.0f / fmaxf((float)dn, 1.0f);
    ushort4 r;
    r.x = f2bf(((a0[0] + a1[0]) + (a2[0] + a3[0])) * inv);
    r.y = f2bf(((a0[1] + a1[1]) + (a2[1] + a3[1])) * inv);
    r.z = f2bf(((a0[2] + a1[2]) + (a2[2] + a3[2])) * inv);
    r.w = f2bf(((a0[3] + a1[3]) + (a2[3] + a3[3])) * inv);
    *(ushort4*)(aggb + (size_t)node * HIDDEN + lane * 4) = r;
}

// ---------------- MFMA layer: hb = bf16(LN(ELU([aggb|hb] @ Wt^T + b_l))) ----------------
__global__ __launch_bounds__(256) void layer_mfma(const unsigned short* __restrict__ aggb,
                                                  const unsigned short* __restrict__ Wt,
                                                  const float* __restrict__ b_l,
                                                  const float* __restrict__ gamma_,
                                                  const float* __restrict__ beta_,
                                                  unsigned short* __restrict__ hb) {
    __shared__ unsigned short At[LBM * AT_STRIDE];
    int t = threadIdx.x;
    int row0 = blockIdx.x * LBM;
    int w = t >> 6;
    int l = t & 63;
    int c = l & 15;
    int g = l >> 4;
    f32x4 acc[2][8];
    #pragma unroll
    for (int fr = 0; fr < 2; ++fr)
        #pragma unroll
        for (int nf = 0; nf < 8; ++nf)
            acc[fr][nf] = (f32x4){0.f, 0.f, 0.f, 0.f};

    for (int kt = 0; kt < 8; ++kt) {
        const unsigned short* Asrc = (kt < 4) ? aggb : hb;
        int kb = (kt & 3) * 32;
        __syncthreads();
        #pragma unroll
        for (int i = 0; i < 2; ++i) {
            int ch = i * 256 + t;
            int row = ch >> 2, cc = ch & 3;
            int node = row0 + row;
            uint4 v = make_uint4(0u, 0u, 0u, 0u);
            if (node < N_NODES)
                v = *(const uint4*)(Asrc + (size_t)node * HIDDEN + kb + cc * 8);
            *(uint4*)&At[row * AT_STRIDE + cc * 8] = v;
        }
        __syncthreads();
        bf16x8 a0 = *(const bf16x8*)&At[(w * 32 + c) * AT_STRIDE + g * 8];
        bf16x8 a1 = *(const bf16x8*)&At[(w * 32 + 16 + c) * AT_STRIDE + g * 8];
        #pragma unroll
        for (int nf = 0; nf < 8; ++nf) {
            bf16x8 b = *(const bf16x8*)(Wt + (size_t)(nf * 16 + c) * 256 + kt * 32 + g * 8);
            acc[0][nf] = __builtin_amdgcn_mfma_f32_16x16x32_bf16(a0, b, acc[0][nf], 0, 0, 0);
            acc[1][nf] = __builtin_amdgcn_mfma_f32_16x16x32_bf16(a1, b, acc[1][nf], 0, 0, 0);
        }
    }
    float bl[8], ga[8], be[8];
    #pragma unroll
    for (int nf = 0; nf < 8; ++nf) {
        int col = nf * 16 + c;
        bl[nf] = b_l[col]; ga[nf] = gamma_[col]; be[nf] = beta_[col];
    }
    const float inv128 = 1.0f / 128.0f;
    #pragma unroll
    for (int fr = 0; fr < 2; ++fr) {
        #pragma unroll
        for (int r = 0; r < 4; ++r) {
            int node = row0 + w * 32 + fr * 16 + g * 4 + r;
            float v[8];
            float s = 0.f, sq = 0.f;
            #pragma unroll
            for (int nf = 0; nf < 8; ++nf) {
                float xv = acc[fr][nf][r] + bl[nf];
                xv = (xv > 0.f) ? xv : expm1f(xv);
                v[nf] = xv; s += xv; sq += xv * xv;
            }
            #pragma unroll
            for (int m = 8; m >= 1; m >>= 1) {
                s += __shfl_xor(s, m, 64);
                sq += __shfl_xor(sq, m, 64);
            }
            float mu = s * inv128;
            float var = sq * inv128 - mu * mu;
            float rstd = rsqrtf(var + LN_EPS);
            if (node < N_NODES) {
                #pragma unroll
                for (int nf = 0; nf < 8; ++nf)
                    hb[(size_t)node * HIDDEN + nf * 16 + c] =
                        f2bf((v[nf] - mu) * rstd * ga[nf] + be[nf]);
            }
        }
    }
}

// ---------------- fused pool + heads (bf16 h) ----------------
__global__ __launch_bounds__(256) void pool_head_kernel(const unsigned short* __restrict__ hb,
                                                        const int* __restrict__ batch,
                                                        const float* __restrict__ W_mem,
                                                        const float* __restrict__ b_mem,
                                                        const float* __restrict__ W_time,
                                                        const float* __restrict__ b_time,
                                                        float* __restrict__ out) {
    __shared__ float red[8][HIDDEN];
    int g = blockIdx.x;
    int t = threadIdx.x;
    int lane = t & 31;
    int grp = t >> 5;
    int lo = 0, hi = N_NODES;
    while (lo < hi) { int mid = (lo + hi) >> 1; if (batch[mid] < g) lo = mid + 1; else hi = mid; }
    int start = lo;
    hi = N_NODES;
    while (lo < hi) { int mid = (lo + hi) >> 1; if (batch[mid] < g + 1) lo = mid + 1; else hi = mid; }
    int end = lo;
    float a0 = 0.f, a1 = 0.f, a2 = 0.f, a3 = 0.f;
    for (int n = start + grp; n < end; n += 8) {
        ushort4 v = *(const ushort4*)(hb + (size_t)n * HIDDEN + lane * 4);
        a0 += bf2f(v.x); a1 += bf2f(v.y); a2 += bf2f(v.z); a3 += bf2f(v.w);
    }
    red[grp][lane * 4 + 0] = a0; red[grp][lane * 4 + 1] = a1;
    red[grp][lane * 4 + 2] = a2; red[grp][lane * 4 + 3] = a3;
    __syncthreads();
    if (t < HIDDEN) {
        float s = 0.f;
        #pragma unroll
        for (int i = 0; i < 8; ++i) s += red[i][t];
        float ic = 1.0f / fmaxf((float)(end - start), 1.0f);
        red[0][t] = s * ic;
    }
    __syncthreads();
    if (t < 64) {
        float p0 = red[0][t], p1 = red[0][t + 64];
        float dm = p0 * W_mem[t] + p1 * W_mem[t + 64];
        float dtv = p0 * W_time[t] + p1 * W_time[t + 64];
        #pragma unroll
        for (int m = 32; m >= 1; m >>= 1) {
            dm += __shfl_xor(dm, m, 64);
            dtv += __shfl_xor(dtv, m, 64);
        }
        if (t == 0) {
            out[g] = dm + b_mem[0];
            out[N_GRAPHS + g] = dtv + b_time[0];
        }
    }
}

extern "C" void kernel_launch(void* const* d_in, const int* in_sizes, int n_in,
                              void* d_out, int out_size, void* d_ws, size_t ws_size,
                              hipStream_t stream) {
    const float* x      = (const float*)d_in[0];
    const int*   edge   = (const int*)d_in[1];
    const int*   batch  = (const int*)d_in[2];
    const float* W_op   = (const float*)d_in[3];
    const float* b_op   = (const float*)d_in[4];
    const float* W_l    = (const float*)d_in[5];
    const float* b_l    = (const float*)d_in[6];
    const float* W_r    = (const float*)d_in[7];
    const float* gamma_ = (const float*)d_in[8];
    const float* beta_  = (const float*)d_in[9];
    const float* W_mem  = (const float*)d_in[10];
    const float* b_mem  = (const float*)d_in[11];
    const float* W_time = (const float*)d_in[12];
    const float* b_time = (const float*)d_in[13];
    const int* src = edge;
    const int* dst = edge + N_EDGES;

    char* ws = (char*)d_ws;
    const size_t hb_bytes = (size_t)N_NODES * HIDDEN * sizeof(unsigned short);  // 25.6MB
    unsigned short* hb    = (unsigned short*)ws;
    unsigned short* aggb  = (unsigned short*)(ws + hb_bytes);
    char*  p       = ws + 2 * hb_bytes;
    unsigned short* Wt = (unsigned short*)p;  p += (size_t)HIDDEN * 2 * HIDDEN * 2;  // 64KB
    int*   offsets = (int*)p;                 p += (size_t)N_NODES * 4;
    int*   ends    = (int*)p;                 p += (size_t)N_NODES * 4;
    int*   csr     = (int*)p;                 p += (size_t)N_EDGES * 4;
    int*   histg   = (int*)p;                 p += 512;
    int*   bbase   = (int*)p;                 p += 512;
    int*   bcur    = (int*)p;                 p += 512;
    // stash (12.8MB) aliases aggb (25.6MB): aggb is dead until first gather,
    // which runs only after csr_bucket has consumed the stash.
    uint2* stash   = (uint2*)aggb;

    hipMemsetAsync(histg, 0, NBUCK * sizeof(int), stream);

    // binned CSR build: hist -> bases -> LDS-sort to stash -> all-LDS finalize
    hist_bucket<<<NBIN, 256, 0, stream>>>(dst, histg);
    scan_bucket<<<1, 128, 0, stream>>>(histg, bbase, bcur);
    bin_pass<<<NBIN, 256, 0, stream>>>(src, dst, bcur, stash);
    csr_bucket<<<NBUCK, 256, 0, stream>>>(stash, bbase, offsets, ends, csr);

    // weights -> bf16 transposed; input projection -> bf16 h
    prep_w<<<128, 256, 0, stream>>>(W_l, W_r, Wt);
    proj_kernel<<<(N_NODES + 63) / 64, 256, 0, stream>>>(x, W_op, b_op, hb);

    // layers
    for (int layer = 0; layer < 2; ++layer) {
        gather_kernel<<<(int)(((size_t)N_NODES * 32 + 255) / 256), 256, 0, stream>>>(
            hb, csr, offsets, ends, aggb);
        layer_mfma<<<(N_NODES + LBM - 1) / LBM, 256, 0, stream>>>(
            aggb, Wt, b_l, gamma_, beta_, hb);
    }

    // fused pooling + heads
    pool_head_kernel<<<N_GRAPHS, 256, 0, stream>>>(hb, batch, W_mem, b_mem, W_time, b_time, (float*)d_out);
}

// Round 14
// 453.148 us; speedup vs baseline: 13.6604x; 1.0022x over previous
//
#include <hip/hip_runtime.h>
#include <hip/hip_bf16.h>
#include <math.h>

#define N_NODES 100000
#define N_EDGES 1600000
#define N_FEAT 32
#define HIDDEN 128
#define N_GRAPHS 256
#define LN_EPS 1e-5f

// CSR-build binning parameters
#define BSHIFT 10
#define BUCKN (1 << BSHIFT)                 // 1024 nodes per bucket
#define NBUCK 98                            // buckets of 1024 nodes
#define EPB 3840                            // edges per bin block
#define NBIN ((N_EDGES + EPB - 1) / EPB)    // 417
#define CAP 24576                           // LDS staging capacity (expected max bucket ~16.9K)

// MFMA layer tile
#define LBM 128                             // rows per block (4 waves x 32)
#define AT_STRIDE 40                        // LDS row stride in ushorts

typedef __attribute__((ext_vector_type(8))) short bf16x8;
typedef __attribute__((ext_vector_type(4))) float f32x4;

__device__ __forceinline__ float bf2f(unsigned short u) {
    return __uint_as_float(((unsigned int)u) << 16);
}
__device__ __forceinline__ unsigned short f2bf(float f) {
    unsigned int u = __float_as_uint(f);
    u += 0x7FFFu + ((u >> 16) & 1u);        // round-to-nearest-even
    return (unsigned short)(u >> 16);
}

// ---------------- bucket histogram ----------------
__global__ __launch_bounds__(256) void hist_bucket(const int* __restrict__ dst,
                                                   int* __restrict__ histg) {
    __shared__ int h[NBUCK];
    int t = threadIdx.x;
    if (t < NBUCK) h[t] = 0;
    __syncthreads();
    int base = blockIdx.x * EPB;
    #pragma unroll
    for (int i = 0; i < EPB / 256; ++i) {
        int e = base + i * 256 + t;
        if (e < N_EDGES) atomicAdd(&h[dst[e] >> BSHIFT], 1);
    }
    __syncthreads();
    if (t < NBUCK && h[t]) atomicAdd(&histg[t], h[t]);
}

// ---------------- bucket base scan ----------------
__global__ __launch_bounds__(128) void scan_bucket(const int* __restrict__ histg,
                                                   int* __restrict__ bbase,
                                                   int* __restrict__ bcur) {
    __shared__ int sb[128];
    int t = threadIdx.x;
    int v = (t < NBUCK) ? histg[t] : 0;
    sb[t] = v;
    __syncthreads();
    for (int off = 1; off < 128; off <<= 1) {
        int x = sb[t];
        if (t >= off) x += sb[t - off];
        __syncthreads();
        sb[t] = x;
        __syncthreads();
    }
    if (t < NBUCK) { bbase[t] = sb[t] - v; bcur[t] = sb[t] - v; }
    if (t == NBUCK - 1) bbase[NBUCK] = sb[t];
}

// ---------------- bin pass (locality-creating LDS counting sort) ----------------
__global__ __launch_bounds__(256) void bin_pass(const int* __restrict__ src,
                                                const int* __restrict__ dst,
                                                int* __restrict__ bcur,
                                                uint2* __restrict__ stash) {
    __shared__ int srcL[EPB];
    __shared__ int dstL[EPB];
    __shared__ int hist[NBUCK], lex[NBUCK], lcur[NBUCK], gbase[NBUCK];
    __shared__ int sb[128];
    int t = threadIdx.x;
    if (t < NBUCK) hist[t] = 0;
    __syncthreads();
    int base = blockIdx.x * EPB;
    #pragma unroll
    for (int i = 0; i < EPB / 256; ++i) {
        int e = base + i * 256 + t;
        if (e < N_EDGES) atomicAdd(&hist[dst[e] >> BSHIFT], 1);
    }
    __syncthreads();
    {
        int v = (t < NBUCK) ? hist[t] : 0;
        if (t < 128) sb[t] = v;
        __syncthreads();
        for (int off = 1; off < 128; off <<= 1) {
            int x = 0;
            if (t < 128) { x = sb[t]; if (t >= off) x += sb[t - off]; }
            __syncthreads();
            if (t < 128) sb[t] = x;
            __syncthreads();
        }
        if (t < NBUCK) {
            int ex = sb[t] - hist[t];
            lex[t] = ex; lcur[t] = ex;
            gbase[t] = atomicAdd(&bcur[t], hist[t]);
        }
    }
    __syncthreads();
    #pragma unroll
    for (int i = 0; i < EPB / 256; ++i) {
        int e = base + i * 256 + t;
        if (e < N_EDGES) {
            int d = dst[e];
            int p = atomicAdd(&lcur[d >> BSHIFT], 1);
            dstL[p] = d; srcL[p] = src[e];
        }
    }
    __syncthreads();
    int n_e = min(EPB, N_EDGES - base);
    #pragma unroll
    for (int i = 0; i < EPB / 256; ++i) {
        int idx = i * 256 + t;
        if (idx < n_e) {
            int lo = 0, hi = NBUCK - 1;
            while (lo < hi) { int mid = (lo + hi + 1) >> 1; if (lex[mid] <= idx) lo = mid; else hi = mid - 1; }
            int g = gbase[lo] + (idx - lex[lo]);
            stash[g] = make_uint2((unsigned)dstL[idx], (unsigned)srcL[idx]);
        }
    }
}

// ---------------- fused CSR finalize: one block per bucket, all-LDS ----------------
__global__ __launch_bounds__(256) void csr_bucket(const uint2* __restrict__ stash,
                                                  const int* __restrict__ bbase,
                                                  int* __restrict__ offsets,
                                                  int* __restrict__ ends,
                                                  int* __restrict__ csr) {
    __shared__ int cnt[BUCKN];     // counts -> cursors -> local ends
    __shared__ int ex[BUCKN];      // exclusive scan (local offsets)
    __shared__ int sb[256];
    __shared__ int srcL[CAP];      // 96KB staging
    int k = blockIdx.x;
    int t = threadIdx.x;
    int beg = bbase[k], end = bbase[k + 1];
    int ne = end - beg;
    #pragma unroll
    for (int i = 0; i < BUCKN / 256; ++i) cnt[i * 256 + t] = 0;
    __syncthreads();
    for (int i = beg + t; i < end; i += 256)
        atomicAdd(&cnt[stash[i].x & (BUCKN - 1)], 1);
    __syncthreads();
    int c0 = cnt[t * 4], c1 = cnt[t * 4 + 1], c2 = cnt[t * 4 + 2], c3 = cnt[t * 4 + 3];
    int gs = c0 + c1 + c2 + c3;
    sb[t] = gs;
    __syncthreads();
    for (int off = 1; off < 256; off <<= 1) {
        int x = sb[t];
        if (t >= off) x += sb[t - off];
        __syncthreads();
        sb[t] = x;
        __syncthreads();
    }
    int gbase_ = sb[t] - gs;
    ex[t * 4]     = gbase_;
    ex[t * 4 + 1] = gbase_ + c0;
    ex[t * 4 + 2] = gbase_ + c0 + c1;
    ex[t * 4 + 3] = gbase_ + c0 + c1 + c2;
    __syncthreads();
    #pragma unroll
    for (int i = 0; i < BUCKN / 256; ++i) cnt[i * 256 + t] = ex[i * 256 + t];
    __syncthreads();
    for (int i = beg + t; i < end; i += 256) {
        uint2 p = stash[i];
        int pos = atomicAdd(&cnt[p.x & (BUCKN - 1)], 1);
        if (pos < CAP) srcL[pos] = (int)p.y;
        else csr[beg + pos] = (int)p.y;   // overflow fallback
    }
    __syncthreads();
    int lim = min(ne, CAP);
    for (int i = t; i < lim; i += 256) csr[beg + i] = srcL[i];
    int nb = k << BSHIFT;
    #pragma unroll
    for (int i = 0; i < BUCKN / 256; ++i) {
        int idx = i * 256 + t;
        int node = nb + idx;
        if (node < N_NODES) {
            offsets[node] = beg + ex[idx];
            ends[node] = beg + cnt[idx];
        }
    }
}

// ---------------- weight prep: Wt[n][k] = bf16 of [W_l; W_r][k][n] ----------------
__global__ __launch_bounds__(256) void prep_w(const float* __restrict__ Wl,
                                              const float* __restrict__ Wr,
                                              unsigned short* __restrict__ Wt) {
    int idx = blockIdx.x * 256 + threadIdx.x;
    if (idx < HIDDEN * 2 * HIDDEN) {
        int n = idx >> 8, k = idx & 255;
        float v = (k < HIDDEN) ? Wl[k * HIDDEN + n] : Wr[(k - HIDDEN) * HIDDEN + n];
        Wt[n * 256 + k] = f2bf(v);
    }
}

// ---------------- input projection -> bf16 h ----------------
__global__ __launch_bounds__(256) void proj_kernel(const float* __restrict__ x,
                                                   const float* __restrict__ W,
                                                   const float* __restrict__ b,
                                                   unsigned short* __restrict__ hb) {
    __shared__ float ws[N_FEAT][HIDDEN];
    __shared__ float bs[HIDDEN];
    __shared__ float xs[64][N_FEAT];
    int t = threadIdx.x;
    #pragma unroll
    for (int i = 0; i < 4; ++i)
        ((float4*)&ws[0][0])[t + i * 256] = ((const float4*)W)[t + i * 256];
    if (t < 32) ((float4*)bs)[t] = ((const float4*)b)[t];
    int base = blockIdx.x * 64;
    #pragma unroll
    for (int i = 0; i < 2; ++i) {
        int f4 = t + i * 256;
        int node = base + (f4 >> 3);
        float4 v = make_float4(0.f, 0.f, 0.f, 0.f);
        if (node < N_NODES) v = ((const float4*)x)[(size_t)node * 8 + (f4 & 7)];
        ((float4*)&xs[0][0])[f4] = v;
    }
    __syncthreads();
    int c0 = (t & 31) * 4;
    int nslot = t >> 5;
    for (int it = 0; it < 8; ++it) {
        int nl = nslot + it * 8;
        int node = base + nl;
        float acc0 = bs[c0], acc1 = bs[c0 + 1], acc2 = bs[c0 + 2], acc3 = bs[c0 + 3];
        #pragma unroll
        for (int k = 0; k < N_FEAT; ++k) {
            float a = xs[nl][k];
            float4 w = *(const float4*)&ws[k][c0];
            acc0 += a * w.x; acc1 += a * w.y; acc2 += a * w.z; acc3 += a * w.w;
        }
        if (node < N_NODES) {
            ushort4 o;
            o.x = f2bf(acc0); o.y = f2bf(acc1); o.z = f2bf(acc2); o.w = f2bf(acc3);
            *(ushort4*)&hb[(size_t)node * HIDDEN + c0] = o;
        }
    }
}

// ---------------- gather (bf16, 16 lanes/node x 16B): agg_b[n] = mean of hb[src] ----------------
// v2: 16-lane groups + uint4 (8 bf16) loads. Same 256B coalesced row read, but
// 4 nodes/wave x 4-deep unroll = 16 rows in flight per wave (2x the MLP of the
// 32-lane version) — gather was latency-bound (42% HBM, 36% VALU, 68% occ).
__global__ __launch_bounds__(256) void gather_kernel(const unsigned short* __restrict__ hb,
                                                     const int* __restrict__ csr,
                                                     const int* __restrict__ offsets,
                                                     const int* __restrict__ ends,
                                                     unsigned short* __restrict__ aggb) {
    int node = (int)(((size_t)blockIdx.x * blockDim.x + threadIdx.x) >> 4);
    int lane = threadIdx.x & 15;   // 16B per lane: 16 x 8 bf16 = 128
    if (node >= N_NODES) return;
    int st = offsets[node];
    int en = ends[node];
    int dn = en - st;
    float a0[8] = {}, a1[8] = {}, a2[8] = {}, a3[8] = {};
    const size_t loff = (size_t)lane * 8;
    int i = st;
    for (; i + 4 <= en; i += 4) {
        int s0 = csr[i], s1 = csr[i + 1], s2 = csr[i + 2], s3 = csr[i + 3];
        uint4 v0 = *(const uint4*)(hb + (size_t)s0 * HIDDEN + loff);
        uint4 v1 = *(const uint4*)(hb + (size_t)s1 * HIDDEN + loff);
        uint4 v2 = *(const uint4*)(hb + (size_t)s2 * HIDDEN + loff);
        uint4 v3 = *(const uint4*)(hb + (size_t)s3 * HIDDEN + loff);
        const unsigned int* u0 = &v0.x;
        const unsigned int* u1 = &v1.x;
        const unsigned int* u2 = &v2.x;
        const unsigned int* u3 = &v3.x;
        #pragma unroll
        for (int j = 0; j < 4; ++j) {
            a0[2*j]   += bf2f((unsigned short)(u0[j] & 0xFFFFu));
            a0[2*j+1] += bf2f((unsigned short)(u0[j] >> 16));
            a1[2*j]   += bf2f((unsigned short)(u1[j] & 0xFFFFu));
            a1[2*j+1] += bf2f((unsigned short)(u1[j] >> 16));
            a2[2*j]   += bf2f((unsigned short)(u2[j] & 0xFFFFu));
            a2[2*j+1] += bf2f((unsigned short)(u2[j] >> 16));
            a3[2*j]   += bf2f((unsigned short)(u3[j] & 0xFFFFu));
            a3[2*j+1] += bf2f((unsigned short)(u3[j] >> 16));
        }
    }
    for (; i < en; ++i) {
        int s0 = csr[i];
        uint4 v0 = *(const uint4*)(hb + (size_t)s0 * HIDDEN + loff);
        const unsigned int* u0 = &v0.x;
        #pragma unroll
        for (int j = 0; j < 4; ++j) {
            a0[2*j]   += bf2f((unsigned short)(u0[j] & 0xFFFFu));
            a0[2*j+1] += bf2f((unsigned short)(u0[j] >> 16));
        }
    }
    float inv = 1.0f / fmaxf((float)dn, 1.0f);
    uint4 r;
    unsigned int* ru = &r.x;
    #pragma unroll
    for (int j = 0; j < 4; ++j) {
        unsigned short lo = f2bf(((a0[2*j]   + a1[2*j])   + (a2[2*j]   + a3[2*j]))   * inv);
        unsigned short hi = f2bf(((a0[2*j+1] + a1[2*j+1]) + (a2[2*j+1] + a3[2*j+1])) * inv);
        ru[j] = (unsigned int)lo | ((unsigned int)hi << 16);
    }
    *(uint4*)(aggb + (size_t)node * HIDDEN + loff) = r;
}

// ---------------- MFMA layer: hb = bf16(LN(ELU([aggb|hb] @ Wt^T + b_l))) ----------------
__global__ __launch_bounds__(256) void layer_mfma(const unsigned short* __restrict__ aggb,
                                                  const unsigned short* __restrict__ Wt,
                                                  const float* __restrict__ b_l,
                                                  const float* __restrict__ gamma_,
                                                  const float* __restrict__ beta_,
                                                  unsigned short* __restrict__ hb) {
    __shared__ unsigned short At[LBM * AT_STRIDE];
    int t = threadIdx.x;
    int row0 = blockIdx.x * LBM;
    int w = t >> 6;
    int l = t & 63;
    int c = l & 15;
    int g = l >> 4;
    f32x4 acc[2][8];
    #pragma unroll
    for (int fr = 0; fr < 2; ++fr)
        #pragma unroll
        for (int nf = 0; nf < 8; ++nf)
            acc[fr][nf] = (f32x4){0.f, 0.f, 0.f, 0.f};

    for (int kt = 0; kt < 8; ++kt) {
        const unsigned short* Asrc = (kt < 4) ? aggb : hb;
        int kb = (kt & 3) * 32;
        __syncthreads();
        #pragma unroll
        for (int i = 0; i < 2; ++i) {
            int ch = i * 256 + t;
            int row = ch >> 2, cc = ch & 3;
            int node = row0 + row;
            uint4 v = make_uint4(0u, 0u, 0u, 0u);
            if (node < N_NODES)
                v = *(const uint4*)(Asrc + (size_t)node * HIDDEN + kb + cc * 8);
            *(uint4*)&At[row * AT_STRIDE + cc * 8] = v;
        }
        __syncthreads();
        bf16x8 a0 = *(const bf16x8*)&At[(w * 32 + c) * AT_STRIDE + g * 8];
        bf16x8 a1 = *(const bf16x8*)&At[(w * 32 + 16 + c) * AT_STRIDE + g * 8];
        #pragma unroll
        for (int nf = 0; nf < 8; ++nf) {
            bf16x8 b = *(const bf16x8*)(Wt + (size_t)(nf * 16 + c) * 256 + kt * 32 + g * 8);
            acc[0][nf] = __builtin_amdgcn_mfma_f32_16x16x32_bf16(a0, b, acc[0][nf], 0, 0, 0);
            acc[1][nf] = __builtin_amdgcn_mfma_f32_16x16x32_bf16(a1, b, acc[1][nf], 0, 0, 0);
        }
    }
    float bl[8], ga[8], be[8];
    #pragma unroll
    for (int nf = 0; nf < 8; ++nf) {
        int col = nf * 16 + c;
        bl[nf] = b_l[col]; ga[nf] = gamma_[col]; be[nf] = beta_[col];
    }
    const float inv128 = 1.0f / 128.0f;
    #pragma unroll
    for (int fr = 0; fr < 2; ++fr) {
        #pragma unroll
        for (int r = 0; r < 4; ++r) {
            int node = row0 + w * 32 + fr * 16 + g * 4 + r;
            float v[8];
            float s = 0.f, sq = 0.f;
            #pragma unroll
            for (int nf = 0; nf < 8; ++nf) {
                float xv = acc[fr][nf][r] + bl[nf];
                xv = (xv > 0.f) ? xv : expm1f(xv);
                v[nf] = xv; s += xv; sq += xv * xv;
            }
            #pragma unroll
            for (int m = 8; m >= 1; m >>= 1) {
                s += __shfl_xor(s, m, 64);
                sq += __shfl_xor(sq, m, 64);
            }
            float mu = s * inv128;
            float var = sq * inv128 - mu * mu;
            float rstd = rsqrtf(var + LN_EPS);
            if (node < N_NODES) {
                #pragma unroll
                for (int nf = 0; nf < 8; ++nf)
                    hb[(size_t)node * HIDDEN + nf * 16 + c] =
                        f2bf((v[nf] - mu) * rstd * ga[nf] + be[nf]);
            }
        }
    }
}

// ---------------- fused pool + heads (bf16 h) ----------------
__global__ __launch_bounds__(256) void pool_head_kernel(const unsigned short* __restrict__ hb,
                                                        const int* __restrict__ batch,
                                                        const float* __restrict__ W_mem,
                                                        const float* __restrict__ b_mem,
                                                        const float* __restrict__ W_time,
                                                        const float* __restrict__ b_time,
                                                        float* __restrict__ out) {
    __shared__ float red[8][HIDDEN];
    int g = blockIdx.x;
    int t = threadIdx.x;
    int lane = t & 31;
    int grp = t >> 5;
    int lo = 0, hi = N_NODES;
    while (lo < hi) { int mid = (lo + hi) >> 1; if (batch[mid] < g) lo = mid + 1; else hi = mid; }
    int start = lo;
    hi = N_NODES;
    while (lo < hi) { int mid = (lo + hi) >> 1; if (batch[mid] < g + 1) lo = mid + 1; else hi = mid; }
    int end = lo;
    float a0 = 0.f, a1 = 0.f, a2 = 0.f, a3 = 0.f;
    for (int n = start + grp; n < end; n += 8) {
        ushort4 v = *(const ushort4*)(hb + (size_t)n * HIDDEN + lane * 4);
        a0 += bf2f(v.x); a1 += bf2f(v.y); a2 += bf2f(v.z); a3 += bf2f(v.w);
    }
    red[grp][lane * 4 + 0] = a0; red[grp][lane * 4 + 1] = a1;
    red[grp][lane * 4 + 2] = a2; red[grp][lane * 4 + 3] = a3;
    __syncthreads();
    if (t < HIDDEN) {
        float s = 0.f;
        #pragma unroll
        for (int i = 0; i < 8; ++i) s += red[i][t];
        float ic = 1.0f / fmaxf((float)(end - start), 1.0f);
        red[0][t] = s * ic;
    }
    __syncthreads();
    if (t < 64) {
        float p0 = red[0][t], p1 = red[0][t + 64];
        float dm = p0 * W_mem[t] + p1 * W_mem[t + 64];
        float dtv = p0 * W_time[t] + p1 * W_time[t + 64];
        #pragma unroll
        for (int m = 32; m >= 1; m >>= 1) {
            dm += __shfl_xor(dm, m, 64);
            dtv += __shfl_xor(dtv, m, 64);
        }
        if (t == 0) {
            out[g] = dm + b_mem[0];
            out[N_GRAPHS + g] = dtv + b_time[0];
        }
    }
}

extern "C" void kernel_launch(void* const* d_in, const int* in_sizes, int n_in,
                              void* d_out, int out_size, void* d_ws, size_t ws_size,
                              hipStream_t stream) {
    const float* x      = (const float*)d_in[0];
    const int*   edge   = (const int*)d_in[1];
    const int*   batch  = (const int*)d_in[2];
    const float* W_op   = (const float*)d_in[3];
    const float* b_op   = (const float*)d_in[4];
    const float* W_l    = (const float*)d_in[5];
    const float* b_l    = (const float*)d_in[6];
    const float* W_r    = (const float*)d_in[7];
    const float* gamma_ = (const float*)d_in[8];
    const float* beta_  = (const float*)d_in[9];
    const float* W_mem  = (const float*)d_in[10];
    const float* b_mem  = (const float*)d_in[11];
    const float* W_time = (const float*)d_in[12];
    const float* b_time = (const float*)d_in[13];
    const int* src = edge;
    const int* dst = edge + N_EDGES;

    char* ws = (char*)d_ws;
    const size_t hb_bytes = (size_t)N_NODES * HIDDEN * sizeof(unsigned short);  // 25.6MB
    unsigned short* hb    = (unsigned short*)ws;
    unsigned short* aggb  = (unsigned short*)(ws + hb_bytes);
    char*  p       = ws + 2 * hb_bytes;
    unsigned short* Wt = (unsigned short*)p;  p += (size_t)HIDDEN * 2 * HIDDEN * 2;  // 64KB
    int*   offsets = (int*)p;                 p += (size_t)N_NODES * 4;
    int*   ends    = (int*)p;                 p += (size_t)N_NODES * 4;
    int*   csr     = (int*)p;                 p += (size_t)N_EDGES * 4;
    int*   histg   = (int*)p;                 p += 512;
    int*   bbase   = (int*)p;                 p += 512;
    int*   bcur    = (int*)p;                 p += 512;
    // stash (12.8MB) aliases aggb (25.6MB): aggb is dead until first gather,
    // which runs only after csr_bucket has consumed the stash.
    uint2* stash   = (uint2*)aggb;

    hipMemsetAsync(histg, 0, NBUCK * sizeof(int), stream);

    // binned CSR build: hist -> bases -> LDS-sort to stash -> all-LDS finalize
    hist_bucket<<<NBIN, 256, 0, stream>>>(dst, histg);
    scan_bucket<<<1, 128, 0, stream>>>(histg, bbase, bcur);
    bin_pass<<<NBIN, 256, 0, stream>>>(src, dst, bcur, stash);
    csr_bucket<<<NBUCK, 256, 0, stream>>>(stash, bbase, offsets, ends, csr);

    // weights -> bf16 transposed; input projection -> bf16 h
    prep_w<<<128, 256, 0, stream>>>(W_l, W_r, Wt);
    proj_kernel<<<(N_NODES + 63) / 64, 256, 0, stream>>>(x, W_op, b_op, hb);

    // layers
    for (int layer = 0; layer < 2; ++layer) {
        gather_kernel<<<(int)(((size_t)N_NODES * 16 + 255) / 256), 256, 0, stream>>>(
            hb, csr, offsets, ends, aggb);
        layer_mfma<<<(N_NODES + LBM - 1) / LBM, 256, 0, stream>>>(
            aggb, Wt, b_l, gamma_, beta_, hb);
    }

    // fused pooling + heads
    pool_head_kernel<<<N_GRAPHS, 256, 0, stream>>>(hb, batch, W_mem, b_mem, W_time, b_time, (float*)d_out);
}